// Round 4
// baseline (1717.318 us; speedup 1.0000x reference)
//
#include <hip/hip_runtime.h>
#include <hip/hip_fp16.h>

typedef _Float16 half8 __attribute__((ext_vector_type(8)));
typedef _Float16 half2v __attribute__((ext_vector_type(2)));
typedef float f32x4 __attribute__((ext_vector_type(4)));

#if __has_builtin(__builtin_amdgcn_fdot2)
#define FDOT2(a, b, c) __builtin_amdgcn_fdot2((a), (b), (c), false)
#else
static __device__ __forceinline__ float FDOT2(half2v a, half2v b, float c) {
  return (float)a[0] * (float)b[0] + (float)a[1] * (float)b[1] + c;
}
#endif
#define H2(v8, p) ((half2v){(v8)[2 * (p)], (v8)[2 * (p) + 1]})

// ---------------- small utility kernels ----------------

__global__ void to_f16_kernel(const float* __restrict__ A, _Float16* __restrict__ B, int n) {
  int i = blockIdx.x * 256 + threadIdx.x;
  if (i < n) B[i] = (_Float16)A[i];
}

// WT[n*K+k] = W[k*N+n]
__global__ void transpose_f16_kernel(const float* __restrict__ W, _Float16* __restrict__ WT, int K, int N) {
  int i = blockIdx.x * 256 + threadIdx.x;
  if (i >= K * N) return;
  int n = i / K, k = i - n * K;
  WT[i] = (_Float16)W[(size_t)k * N + n];
}

// in-degree histogram + per-dst edge_attr sum (for self-loop fill_value='mean')
__global__ void edge_hist_kernel(const int* __restrict__ dst0, const float* __restrict__ ea,
                                 int* __restrict__ deg, float* __restrict__ lsum, int E) {
  int i = blockIdx.x * 256 + threadIdx.x;
  if (i >= E * 16) return;
  int e = i >> 4, k = i & 15;
  int d = dst0[e];
  if (k == 0) atomicAdd(&deg[d], 1);
  atomicAdd(&lsum[(size_t)d * 16 + k], ea[i]);
}

// self-loop attr -> f16, written into ea16[E..E+N)
__global__ void loop_norm16_kernel(const float* __restrict__ lsum, const int* __restrict__ deg,
                                   _Float16* __restrict__ dst16, int N) {
  int i = blockIdx.x * 256 + threadIdx.x;
  if (i >= N * 16) return;
  float c = (float)deg[i >> 4];
  dst16[i] = (_Float16)(lsum[i] / fmaxf(c, 1.0f));
}

// exclusive scan of (deg[v]+1) -> offs[0..N], single block
__global__ __launch_bounds__(1024) void scan_kernel(const int* __restrict__ deg, int* __restrict__ offs, int N) {
  __shared__ int part[1024];
  int t = threadIdx.x;
  int chunk = (N + 1023) / 1024;
  int b = t * chunk, e = min(b + chunk, N);
  int s = 0;
  for (int i = b; i < e; i++) s += deg[i] + 1;
  part[t] = s;
  __syncthreads();
  for (int off = 1; off < 1024; off <<= 1) {
    int v = (t >= off) ? part[t - off] : 0;
    __syncthreads();
    part[t] += v;
    __syncthreads();
  }
  int run = (t == 0) ? 0 : part[t - 1];
  for (int i = b; i < e; i++) { offs[i] = run; run += deg[i] + 1; }
  if (t == 1023) offs[N] = part[1023];
}

// scatter (eid, src) pairs into CSR buckets; self-loop eid=E+v at slot offs[v]+deg[v]; +2 pad
__global__ void csr_fill_kernel(const int* __restrict__ src0, const int* __restrict__ dst0,
                                const int* __restrict__ offs, const int* __restrict__ deg,
                                int* __restrict__ cnt, int2* __restrict__ csr2, int E, int N) {
  int i = blockIdx.x * 256 + threadIdx.x;
  if (i == 0) {
    int EP = E + N;
    csr2[EP] = make_int2(0, 0);
    csr2[EP + 1] = make_int2(0, 0);
  }
  if (i < E) {
    int d = dst0[i];
    int p = offs[d] + atomicAdd(&cnt[d], 1);
    csr2[p] = make_int2(i, src0[i]);
  } else if (i < E + N) {
    int v = i - E;
    int p = offs[v] + deg[v];
    csr2[p] = make_int2(E + v, v);
  }
}

// ---------------- GEMM: C[M,N] = A[M,K](f16) * BT[N,K](f16) + bias ----------------
template <bool RELU, bool OUT_F32>
__global__ __launch_bounds__(256) void gemm_f16(const _Float16* __restrict__ A,
                                                const _Float16* __restrict__ BT,
                                                const float* __restrict__ bias,
                                                void* __restrict__ C,
                                                int M, int K, int Nfull) {
  __shared__ _Float16 As[128 * 40];
  __shared__ _Float16 Bs[128 * 40];
  int t = threadIdx.x;
  int m0 = blockIdx.x * 128;
  int n0 = blockIdx.y * 128;
  int l = t & 63, w = t >> 6;
  int wm = w & 1, wn = w >> 1;
  int lr = l & 15, lq = l >> 4;

  f32x4 acc[4][4];
#pragma unroll
  for (int i = 0; i < 4; i++)
#pragma unroll
    for (int j = 0; j < 4; j++) acc[i][j] = (f32x4){0.f, 0.f, 0.f, 0.f};

  const half8 hzero = {0, 0, 0, 0, 0, 0, 0, 0};
  int srow = t >> 2;
  int sq = (t & 3) * 8;

  for (int kk = 0; kk < K; kk += 32) {
    half8 a0 = (m0 + srow < M) ? *(const half8*)(A + (size_t)(m0 + srow) * K + kk + sq) : hzero;
    half8 a1 = (m0 + srow + 64 < M) ? *(const half8*)(A + (size_t)(m0 + srow + 64) * K + kk + sq) : hzero;
    half8 b0 = (n0 + srow < Nfull) ? *(const half8*)(BT + (size_t)(n0 + srow) * K + kk + sq) : hzero;
    half8 b1 = (n0 + srow + 64 < Nfull) ? *(const half8*)(BT + (size_t)(n0 + srow + 64) * K + kk + sq) : hzero;
    __syncthreads();
    *(half8*)&As[srow * 40 + sq] = a0;
    *(half8*)&As[(srow + 64) * 40 + sq] = a1;
    *(half8*)&Bs[srow * 40 + sq] = b0;
    *(half8*)&Bs[(srow + 64) * 40 + sq] = b1;
    __syncthreads();
    half8 af[4], bf[4];
#pragma unroll
    for (int mi = 0; mi < 4; mi++) af[mi] = *(const half8*)&As[(wm * 64 + mi * 16 + lr) * 40 + lq * 8];
#pragma unroll
    for (int ni = 0; ni < 4; ni++) bf[ni] = *(const half8*)&Bs[(wn * 64 + ni * 16 + lr) * 40 + lq * 8];
#pragma unroll
    for (int mi = 0; mi < 4; mi++)
#pragma unroll
      for (int ni = 0; ni < 4; ni++)
        acc[mi][ni] = __builtin_amdgcn_mfma_f32_16x16x32_f16(af[mi], bf[ni], acc[mi][ni], 0, 0, 0);
  }

#pragma unroll
  for (int ni = 0; ni < 4; ni++) {
    int col = n0 + wn * 64 + ni * 16 + lr;
    if (col >= Nfull) continue;
    float bv = bias[col];
#pragma unroll
    for (int mi = 0; mi < 4; mi++) {
#pragma unroll
      for (int r = 0; r < 4; r++) {
        int row = m0 + wm * 64 + mi * 16 + lq * 4 + r;
        if (row >= M) continue;
        float v = acc[mi][ni][r] + bv;
        if (RELU) v = fmaxf(v, 0.f);
        if (OUT_F32) ((float*)C)[(size_t)row * Nfull + col] = v;
        else ((_Float16*)C)[(size_t)row * Nfull + col] = (_Float16)v;
      }
    }
  }
}

// ---------------- fused GATv2 edge pass: wave per node, online softmax ----------------
// grid 1536 = 6 blocks/CU (VGPR 76 -> 6 waves/SIMD fit); launch_bounds caps VGPR at 85.
__global__ __launch_bounds__(256, 6) void gat_fused_kernel(
    const _Float16* __restrict__ xl, const _Float16* __restrict__ xr,
    const int2* __restrict__ csr2, const int* __restrict__ offs,
    const _Float16* __restrict__ ea16,   // [E+N][16]
    const _Float16* __restrict__ WeP,    // [512][16]  (WeP[c][k] = We[k][c])
    const float* __restrict__ att, const float* __restrict__ bias,
    _Float16* __restrict__ hout, int N) {
  int l = threadIdx.x & 63;
  int h = l >> 4;
  int c0 = l * 8;

  half8 Wf0[8], Wf1[8];
#pragma unroll
  for (int j = 0; j < 8; j++) {
    Wf0[j] = *(const half8*)(WeP + (size_t)(c0 + j) * 16);
    Wf1[j] = *(const half8*)(WeP + (size_t)(c0 + j) * 16 + 8);
  }
  float attf[8];
  const float* attp = att + h * 128 + (l & 15) * 8;
#pragma unroll
  for (int j = 0; j < 8; j++) attf[j] = attp[j];

  int wid = blockIdx.x * 4 + (threadIdx.x >> 6);
  int nw = gridDim.x * 4;

  for (int v = wid; v < N; v += nw) {
    int b = offs[v], e2 = offs[v + 1];
    half8 xrv = *(const half8*)(xr + (size_t)v * 512 + c0);
    float xrf[8];
#pragma unroll
    for (int jj = 0; jj < 8; jj++) xrf[jj] = (float)xrv[jj];

    // pipeline: gather regs for edge j; (eid,src) resolved for edge j+1
    int2 cA = csr2[b];
    half8 xsA = *(const half8*)(xl + (size_t)cA.y * 512 + c0);
    half8 ea0A = *(const half8*)(ea16 + (size_t)cA.x * 16);
    half8 ea1A = *(const half8*)(ea16 + (size_t)cA.x * 16 + 8);
    int2 cB = csr2[b + 1];

    float m = -1e30f, den = 0.f;
    float acc[8];
#pragma unroll
    for (int j = 0; j < 8; j++) acc[j] = 0.f;

    for (int j = b; j < e2; j++) {
      half8 xs = xsA, ea0 = ea0A, ea1 = ea1A;
      // issue next edge's gathers (indices already resolved), then resolve j+2 indices
      xsA = *(const half8*)(xl + (size_t)cB.y * 512 + c0);
      ea0A = *(const half8*)(ea16 + (size_t)cB.x * 16);
      ea1A = *(const half8*)(ea16 + (size_t)cB.x * 16 + 8);
      cB = csr2[j + 2];   // padded arrays: safe

      float xsf[8];
#pragma unroll
      for (int jj = 0; jj < 8; jj++) xsf[jj] = (float)xs[jj];

      float partial = 0.f;
#pragma unroll
      for (int jj = 0; jj < 8; jj++) {
        float ef = 0.f;
#pragma unroll
        for (int p = 0; p < 4; p++) ef = FDOT2(H2(ea0, p), H2(Wf0[jj], p), ef);
#pragma unroll
        for (int p = 0; p < 4; p++) ef = FDOT2(H2(ea1, p), H2(Wf1[jj], p), ef);
        float val = xsf[jj] + xrf[jj] + ef;
        val = val > 0.f ? val : 0.2f * val;
        partial = fmaf(val, attf[jj], partial);
      }
#pragma unroll
      for (int off2 = 1; off2 < 16; off2 <<= 1) partial += __shfl_xor(partial, off2);
      // online softmax (per head; all 16 lanes of a head group agree on `partial`)
      float mn = fmaxf(m, partial);
      float sc = __expf(m - mn);
      float al = __expf(partial - mn);
      den = den * sc + al;
#pragma unroll
      for (int jj = 0; jj < 8; jj++) acc[jj] = fmaf(acc[jj], sc, al * xsf[jj]);
      m = mn;
    }
    float rd = 1.f / (den + 1e-16f);
    half8 o;
#pragma unroll
    for (int jj = 0; jj < 8; jj++) o[jj] = (_Float16)(fmaf(acc[jj], rd, bias[c0 + jj]));
    *(half8*)(hout + (size_t)v * 512 + c0) = o;
  }
}

// ---------------- launcher ----------------

extern "C" void kernel_launch(void* const* d_in, const int* in_sizes, int n_in,
                              void* d_out, int out_size, void* d_ws, size_t ws_size,
                              hipStream_t stream) {
  (void)n_in; (void)out_size; (void)ws_size;
  const float* x    = (const float*)d_in[0];
  const int*   ei   = (const int*)d_in[1];
  const float* ea   = (const float*)d_in[2];
  const float* Wl1  = (const float*)d_in[3];
  const float* bl1  = (const float*)d_in[4];
  const float* Wr1  = (const float*)d_in[5];
  const float* br1  = (const float*)d_in[6];
  const float* We1  = (const float*)d_in[7];
  const float* att1 = (const float*)d_in[8];
  const float* bias1= (const float*)d_in[9];
  const float* Wl2  = (const float*)d_in[10];
  const float* bl2  = (const float*)d_in[11];
  const float* Wr2  = (const float*)d_in[12];
  const float* br2  = (const float*)d_in[13];
  const float* We2  = (const float*)d_in[14];
  const float* att2 = (const float*)d_in[15];
  const float* bias2= (const float*)d_in[16];
  const float* Wd1  = (const float*)d_in[17];
  const float* bd1  = (const float*)d_in[18];
  const float* Wd2  = (const float*)d_in[19];
  const float* bd2  = (const float*)d_in[20];

  const int N = in_sizes[0] / 128;
  const int E = in_sizes[1] / 2;
  const int EP = E + N;
  const int* src0 = ei;
  const int* dst0 = ei + E;

  char* ws = (char*)d_ws;
  size_t off = 0;
  auto alloc = [&](size_t bytes) -> void* {
    void* p = ws + off;
    off += (bytes + 255) & ~(size_t)255;
    return p;
  };

  // deg | cnt | lsum contiguous -> single memset
  int*   deg   = (int*)alloc((size_t)N * 72);
  int*   cnt   = deg + N;
  float* lsum  = (float*)(cnt + N);
  int*   offs  = (int*)alloc(((size_t)N + 1) * 4);
  int2*  csr2  = (int2*)alloc(((size_t)EP + 2) * 8);
  _Float16* ea16 = (_Float16*)alloc((size_t)EP * 16 * 2);
  _Float16* x16  = (_Float16*)alloc((size_t)N * 128 * 2);
  _Float16* xl16 = (_Float16*)alloc((size_t)N * 512 * 2);
  _Float16* xr16 = (_Float16*)alloc((size_t)N * 512 * 2);
  _Float16* h16  = (_Float16*)alloc((size_t)N * 512 * 2);
  _Float16* WlT1 = (_Float16*)alloc(128 * 512 * 2);
  _Float16* WrT1 = (_Float16*)alloc(128 * 512 * 2);
  _Float16* WlT2 = (_Float16*)alloc(512 * 512 * 2);
  _Float16* WrT2 = (_Float16*)alloc(512 * 512 * 2);
  _Float16* WdT1 = (_Float16*)alloc(512 * 512 * 2);
  _Float16* WdT2 = (_Float16*)alloc(512 * 64 * 2);
  _Float16* WeP1 = (_Float16*)alloc(512 * 16 * 2);
  _Float16* WeP2 = (_Float16*)alloc(512 * 16 * 2);
  _Float16* t16 = xr16;  // decoder hidden reuses xr buffer (dead by then)

  hipMemsetAsync(deg, 0, (size_t)N * 72, stream);

  int g;
  g = (N * 128 + 255) / 256; to_f16_kernel<<<g, 256, 0, stream>>>(x, x16, N * 128);
  g = (E * 16 + 255) / 256;  to_f16_kernel<<<g, 256, 0, stream>>>(ea, ea16, E * 16);
  g = (128 * 512 + 255) / 256;
  transpose_f16_kernel<<<g, 256, 0, stream>>>(Wl1, WlT1, 128, 512);
  transpose_f16_kernel<<<g, 256, 0, stream>>>(Wr1, WrT1, 128, 512);
  g = (512 * 512 + 255) / 256;
  transpose_f16_kernel<<<g, 256, 0, stream>>>(Wl2, WlT2, 512, 512);
  transpose_f16_kernel<<<g, 256, 0, stream>>>(Wr2, WrT2, 512, 512);
  transpose_f16_kernel<<<g, 256, 0, stream>>>(Wd1, WdT1, 512, 512);
  g = (512 * 64 + 255) / 256;
  transpose_f16_kernel<<<g, 256, 0, stream>>>(Wd2, WdT2, 512, 64);
  g = (16 * 512 + 255) / 256;
  transpose_f16_kernel<<<g, 256, 0, stream>>>(We1, WeP1, 16, 512);
  transpose_f16_kernel<<<g, 256, 0, stream>>>(We2, WeP2, 16, 512);

  dim3 gg((N + 127) / 128, 4), gb(256);
  gemm_f16<false, false><<<gg, gb, 0, stream>>>(x16, WlT1, bl1, xl16, N, 128, 512);
  gemm_f16<false, false><<<gg, gb, 0, stream>>>(x16, WrT1, br1, xr16, N, 128, 512);

  g = (E * 16 + 255) / 256; edge_hist_kernel<<<g, 256, 0, stream>>>(dst0, ea, deg, lsum, E);
  g = (N * 16 + 255) / 256; loop_norm16_kernel<<<g, 256, 0, stream>>>(lsum, deg, ea16 + (size_t)E * 16, N);
  scan_kernel<<<1, 1024, 0, stream>>>(deg, offs, N);
  g = (EP + 255) / 256;
  csr_fill_kernel<<<g, 256, 0, stream>>>(src0, dst0, offs, deg, cnt, csr2, E, N);

  const int FGRID = 1536;  // 6 blocks/CU resident (VGPR 76 -> 6 waves/SIMD); grid-stride over nodes

  // ---- GAT layer 1 (fused logits+softmax+aggregate) ----
  gat_fused_kernel<<<FGRID, 256, 0, stream>>>(xl16, xr16, csr2, offs,
                                              ea16, WeP1, att1, bias1, h16, N);

  // ---- GAT layer 2 ----
  gemm_f16<false, false><<<gg, gb, 0, stream>>>(h16, WlT2, bl2, xl16, N, 512, 512);
  gemm_f16<false, false><<<gg, gb, 0, stream>>>(h16, WrT2, br2, xr16, N, 512, 512);
  gat_fused_kernel<<<FGRID, 256, 0, stream>>>(xl16, xr16, csr2, offs,
                                              ea16, WeP2, att2, bias2, h16, N);

  // ---- decoder ----
  gemm_f16<true, false><<<gg, gb, 0, stream>>>(h16, WdT1, bd1, t16, N, 512, 512);
  dim3 gd((N + 127) / 128, 1);
  gemm_f16<false, true><<<gd, gb, 0, stream>>>(t16, WdT2, bd2, d_out, N, 512, 64);
}

// Round 5
// 707.644 us; speedup vs baseline: 2.4268x; 2.4268x over previous
//
#include <hip/hip_runtime.h>
#include <hip/hip_fp16.h>

typedef _Float16 half8 __attribute__((ext_vector_type(8)));
typedef _Float16 half2v __attribute__((ext_vector_type(2)));
typedef float f32x4 __attribute__((ext_vector_type(4)));

#if __has_builtin(__builtin_amdgcn_fdot2)
#define FDOT2(a, b, c) __builtin_amdgcn_fdot2((a), (b), (c), false)
#else
static __device__ __forceinline__ float FDOT2(half2v a, half2v b, float c) {
  return (float)a[0] * (float)b[0] + (float)a[1] * (float)b[1] + c;
}
#endif
#define H2(v8, p) ((half2v){(v8)[2 * (p)], (v8)[2 * (p) + 1]})

// ---------------- small utility kernels ----------------

__global__ void to_f16_kernel(const float* __restrict__ A, _Float16* __restrict__ B, int n) {
  int i = blockIdx.x * 256 + threadIdx.x;
  if (i < n) B[i] = (_Float16)A[i];
}

// WT[n*K+k] = W[k*N+n]
__global__ void transpose_f16_kernel(const float* __restrict__ W, _Float16* __restrict__ WT, int K, int N) {
  int i = blockIdx.x * 256 + threadIdx.x;
  if (i >= K * N) return;
  int n = i / K, k = i - n * K;
  WT[i] = (_Float16)W[(size_t)k * N + n];
}

// in-degree histogram + per-dst edge_attr sum (for self-loop fill_value='mean')
__global__ void edge_hist_kernel(const int* __restrict__ dst0, const float* __restrict__ ea,
                                 int* __restrict__ deg, float* __restrict__ lsum, int E) {
  int i = blockIdx.x * 256 + threadIdx.x;
  if (i >= E * 16) return;
  int e = i >> 4, k = i & 15;
  int d = dst0[e];
  if (k == 0) atomicAdd(&deg[d], 1);
  atomicAdd(&lsum[(size_t)d * 16 + k], ea[i]);
}

// self-loop attr -> f16, written into ea16[E..E+N)
__global__ void loop_norm16_kernel(const float* __restrict__ lsum, const int* __restrict__ deg,
                                   _Float16* __restrict__ dst16, int N) {
  int i = blockIdx.x * 256 + threadIdx.x;
  if (i >= N * 16) return;
  float c = (float)deg[i >> 4];
  dst16[i] = (_Float16)(lsum[i] / fmaxf(c, 1.0f));
}

// exclusive scan of (deg[v]+1) -> offs[0..N], single block
__global__ __launch_bounds__(1024) void scan_kernel(const int* __restrict__ deg, int* __restrict__ offs, int N) {
  __shared__ int part[1024];
  int t = threadIdx.x;
  int chunk = (N + 1023) / 1024;
  int b = t * chunk, e = min(b + chunk, N);
  int s = 0;
  for (int i = b; i < e; i++) s += deg[i] + 1;
  part[t] = s;
  __syncthreads();
  for (int off = 1; off < 1024; off <<= 1) {
    int v = (t >= off) ? part[t - off] : 0;
    __syncthreads();
    part[t] += v;
    __syncthreads();
  }
  int run = (t == 0) ? 0 : part[t - 1];
  for (int i = b; i < e; i++) { offs[i] = run; run += deg[i] + 1; }
  if (t == 1023) offs[N] = part[1023];
}

// scatter (eid, src) pairs into CSR buckets; self-loop eid=E+v at slot offs[v]+deg[v]; +2 pad
__global__ void csr_fill_kernel(const int* __restrict__ src0, const int* __restrict__ dst0,
                                const int* __restrict__ offs, const int* __restrict__ deg,
                                int* __restrict__ cnt, int2* __restrict__ csr2, int E, int N) {
  int i = blockIdx.x * 256 + threadIdx.x;
  if (i == 0) {
    int EP = E + N;
    csr2[EP] = make_int2(0, 0);
    csr2[EP + 1] = make_int2(0, 0);
  }
  if (i < E) {
    int d = dst0[i];
    int p = offs[d] + atomicAdd(&cnt[d], 1);
    csr2[p] = make_int2(i, src0[i]);
  } else if (i < E + N) {
    int v = i - E;
    int p = offs[v] + deg[v];
    csr2[p] = make_int2(E + v, v);
  }
}

// ---------------- GEMM: C[M,N] = A[M,K](f16) * BT[N,K](f16) + bias ----------------
template <bool RELU, bool OUT_F32>
__global__ __launch_bounds__(256) void gemm_f16(const _Float16* __restrict__ A,
                                                const _Float16* __restrict__ BT,
                                                const float* __restrict__ bias,
                                                void* __restrict__ C,
                                                int M, int K, int Nfull) {
  __shared__ _Float16 As[128 * 40];
  __shared__ _Float16 Bs[128 * 40];
  int t = threadIdx.x;
  int m0 = blockIdx.x * 128;
  int n0 = blockIdx.y * 128;
  int l = t & 63, w = t >> 6;
  int wm = w & 1, wn = w >> 1;
  int lr = l & 15, lq = l >> 4;

  f32x4 acc[4][4];
#pragma unroll
  for (int i = 0; i < 4; i++)
#pragma unroll
    for (int j = 0; j < 4; j++) acc[i][j] = (f32x4){0.f, 0.f, 0.f, 0.f};

  const half8 hzero = {0, 0, 0, 0, 0, 0, 0, 0};
  int srow = t >> 2;
  int sq = (t & 3) * 8;

  for (int kk = 0; kk < K; kk += 32) {
    half8 a0 = (m0 + srow < M) ? *(const half8*)(A + (size_t)(m0 + srow) * K + kk + sq) : hzero;
    half8 a1 = (m0 + srow + 64 < M) ? *(const half8*)(A + (size_t)(m0 + srow + 64) * K + kk + sq) : hzero;
    half8 b0 = (n0 + srow < Nfull) ? *(const half8*)(BT + (size_t)(n0 + srow) * K + kk + sq) : hzero;
    half8 b1 = (n0 + srow + 64 < Nfull) ? *(const half8*)(BT + (size_t)(n0 + srow + 64) * K + kk + sq) : hzero;
    __syncthreads();
    *(half8*)&As[srow * 40 + sq] = a0;
    *(half8*)&As[(srow + 64) * 40 + sq] = a1;
    *(half8*)&Bs[srow * 40 + sq] = b0;
    *(half8*)&Bs[(srow + 64) * 40 + sq] = b1;
    __syncthreads();
    half8 af[4], bf[4];
#pragma unroll
    for (int mi = 0; mi < 4; mi++) af[mi] = *(const half8*)&As[(wm * 64 + mi * 16 + lr) * 40 + lq * 8];
#pragma unroll
    for (int ni = 0; ni < 4; ni++) bf[ni] = *(const half8*)&Bs[(wn * 64 + ni * 16 + lr) * 40 + lq * 8];
#pragma unroll
    for (int mi = 0; mi < 4; mi++)
#pragma unroll
      for (int ni = 0; ni < 4; ni++)
        acc[mi][ni] = __builtin_amdgcn_mfma_f32_16x16x32_f16(af[mi], bf[ni], acc[mi][ni], 0, 0, 0);
  }

#pragma unroll
  for (int ni = 0; ni < 4; ni++) {
    int col = n0 + wn * 64 + ni * 16 + lr;
    if (col >= Nfull) continue;
    float bv = bias[col];
#pragma unroll
    for (int mi = 0; mi < 4; mi++) {
#pragma unroll
      for (int r = 0; r < 4; r++) {
        int row = m0 + wm * 64 + mi * 16 + lq * 4 + r;
        if (row >= M) continue;
        float v = acc[mi][ni][r] + bv;
        if (RELU) v = fmaxf(v, 0.f);
        if (OUT_F32) ((float*)C)[(size_t)row * Nfull + col] = v;
        else ((_Float16*)C)[(size_t)row * Nfull + col] = (_Float16)v;
      }
    }
  }
}

// ---------------- fused GATv2 edge pass: wave per node, online softmax ----------------
// NOTE: plain __launch_bounds__(256) — round 4 showed that declaring min-waves/EU
// makes the allocator spill the We fragments (VGPR 76->40, FETCH 176MB->2.1GB).
// Residency comes from grid size alone: VGPR 76 -> 6 blocks/CU fit in HW.
__global__ __launch_bounds__(256) void gat_fused_kernel(
    const _Float16* __restrict__ xl, const _Float16* __restrict__ xr,
    const int2* __restrict__ csr2, const int* __restrict__ offs,
    const _Float16* __restrict__ ea16,   // [E+N][16]
    const _Float16* __restrict__ WeP,    // [512][16]  (WeP[c][k] = We[k][c])
    const float* __restrict__ att, const float* __restrict__ bias,
    _Float16* __restrict__ hout, int N) {
  int l = threadIdx.x & 63;
  int h = l >> 4;
  int c0 = l * 8;

  half8 Wf0[8], Wf1[8];
#pragma unroll
  for (int j = 0; j < 8; j++) {
    Wf0[j] = *(const half8*)(WeP + (size_t)(c0 + j) * 16);
    Wf1[j] = *(const half8*)(WeP + (size_t)(c0 + j) * 16 + 8);
  }
  float attf[8];
  const float* attp = att + h * 128 + (l & 15) * 8;
#pragma unroll
  for (int j = 0; j < 8; j++) attf[j] = attp[j];

  int wid = blockIdx.x * 4 + (threadIdx.x >> 6);
  int nw = gridDim.x * 4;

  for (int v = wid; v < N; v += nw) {
    int b = offs[v], e2 = offs[v + 1];
    half8 xrv = *(const half8*)(xr + (size_t)v * 512 + c0);
    float xrf[8];
#pragma unroll
    for (int jj = 0; jj < 8; jj++) xrf[jj] = (float)xrv[jj];

    // pipeline: gather regs for edge j; (eid,src) resolved for edge j+1
    int2 cA = csr2[b];
    half8 xsA = *(const half8*)(xl + (size_t)cA.y * 512 + c0);
    half8 ea0A = *(const half8*)(ea16 + (size_t)cA.x * 16);
    half8 ea1A = *(const half8*)(ea16 + (size_t)cA.x * 16 + 8);
    int2 cB = csr2[b + 1];

    float m = -1e30f, den = 0.f;
    float acc[8];
#pragma unroll
    for (int j = 0; j < 8; j++) acc[j] = 0.f;

    for (int j = b; j < e2; j++) {
      half8 xs = xsA, ea0 = ea0A, ea1 = ea1A;
      // issue next edge's gathers (indices already resolved), then resolve j+2 indices
      xsA = *(const half8*)(xl + (size_t)cB.y * 512 + c0);
      ea0A = *(const half8*)(ea16 + (size_t)cB.x * 16);
      ea1A = *(const half8*)(ea16 + (size_t)cB.x * 16 + 8);
      cB = csr2[j + 2];   // padded arrays: safe

      float xsf[8];
#pragma unroll
      for (int jj = 0; jj < 8; jj++) xsf[jj] = (float)xs[jj];

      float partial = 0.f;
#pragma unroll
      for (int jj = 0; jj < 8; jj++) {
        float ef = 0.f;
#pragma unroll
        for (int p = 0; p < 4; p++) ef = FDOT2(H2(ea0, p), H2(Wf0[jj], p), ef);
#pragma unroll
        for (int p = 0; p < 4; p++) ef = FDOT2(H2(ea1, p), H2(Wf1[jj], p), ef);
        float val = xsf[jj] + xrf[jj] + ef;
        val = val > 0.f ? val : 0.2f * val;
        partial = fmaf(val, attf[jj], partial);
      }
#pragma unroll
      for (int off2 = 1; off2 < 16; off2 <<= 1) partial += __shfl_xor(partial, off2);
      // online softmax (per head; all 16 lanes of a head group agree on `partial`)
      float mn = fmaxf(m, partial);
      float sc = __expf(m - mn);
      float al = __expf(partial - mn);
      den = den * sc + al;
#pragma unroll
      for (int jj = 0; jj < 8; jj++) acc[jj] = fmaf(acc[jj], sc, al * xsf[jj]);
      m = mn;
    }
    float rd = 1.f / (den + 1e-16f);
    half8 o;
#pragma unroll
    for (int jj = 0; jj < 8; jj++) o[jj] = (_Float16)(fmaf(acc[jj], rd, bias[c0 + jj]));
    *(half8*)(hout + (size_t)v * 512 + c0) = o;
  }
}

// ---------------- launcher ----------------

extern "C" void kernel_launch(void* const* d_in, const int* in_sizes, int n_in,
                              void* d_out, int out_size, void* d_ws, size_t ws_size,
                              hipStream_t stream) {
  (void)n_in; (void)out_size; (void)ws_size;
  const float* x    = (const float*)d_in[0];
  const int*   ei   = (const int*)d_in[1];
  const float* ea   = (const float*)d_in[2];
  const float* Wl1  = (const float*)d_in[3];
  const float* bl1  = (const float*)d_in[4];
  const float* Wr1  = (const float*)d_in[5];
  const float* br1  = (const float*)d_in[6];
  const float* We1  = (const float*)d_in[7];
  const float* att1 = (const float*)d_in[8];
  const float* bias1= (const float*)d_in[9];
  const float* Wl2  = (const float*)d_in[10];
  const float* bl2  = (const float*)d_in[11];
  const float* Wr2  = (const float*)d_in[12];
  const float* br2  = (const float*)d_in[13];
  const float* We2  = (const float*)d_in[14];
  const float* att2 = (const float*)d_in[15];
  const float* bias2= (const float*)d_in[16];
  const float* Wd1  = (const float*)d_in[17];
  const float* bd1  = (const float*)d_in[18];
  const float* Wd2  = (const float*)d_in[19];
  const float* bd2  = (const float*)d_in[20];

  const int N = in_sizes[0] / 128;
  const int E = in_sizes[1] / 2;
  const int EP = E + N;
  const int* src0 = ei;
  const int* dst0 = ei + E;

  char* ws = (char*)d_ws;
  size_t off = 0;
  auto alloc = [&](size_t bytes) -> void* {
    void* p = ws + off;
    off += (bytes + 255) & ~(size_t)255;
    return p;
  };

  // deg | cnt | lsum contiguous -> single memset
  int*   deg   = (int*)alloc((size_t)N * 72);
  int*   cnt   = deg + N;
  float* lsum  = (float*)(cnt + N);
  int*   offs  = (int*)alloc(((size_t)N + 1) * 4);
  int2*  csr2  = (int2*)alloc(((size_t)EP + 2) * 8);
  _Float16* ea16 = (_Float16*)alloc((size_t)EP * 16 * 2);
  _Float16* x16  = (_Float16*)alloc((size_t)N * 128 * 2);
  _Float16* xl16 = (_Float16*)alloc((size_t)N * 512 * 2);
  _Float16* xr16 = (_Float16*)alloc((size_t)N * 512 * 2);
  _Float16* h16  = (_Float16*)alloc((size_t)N * 512 * 2);
  _Float16* WlT1 = (_Float16*)alloc(128 * 512 * 2);
  _Float16* WrT1 = (_Float16*)alloc(128 * 512 * 2);
  _Float16* WlT2 = (_Float16*)alloc(512 * 512 * 2);
  _Float16* WrT2 = (_Float16*)alloc(512 * 512 * 2);
  _Float16* WdT1 = (_Float16*)alloc(512 * 512 * 2);
  _Float16* WdT2 = (_Float16*)alloc(512 * 64 * 2);
  _Float16* WeP1 = (_Float16*)alloc(512 * 16 * 2);
  _Float16* WeP2 = (_Float16*)alloc(512 * 16 * 2);
  _Float16* t16 = xr16;  // decoder hidden reuses xr buffer (dead by then)

  hipMemsetAsync(deg, 0, (size_t)N * 72, stream);

  int g;
  g = (N * 128 + 255) / 256; to_f16_kernel<<<g, 256, 0, stream>>>(x, x16, N * 128);
  g = (E * 16 + 255) / 256;  to_f16_kernel<<<g, 256, 0, stream>>>(ea, ea16, E * 16);
  g = (128 * 512 + 255) / 256;
  transpose_f16_kernel<<<g, 256, 0, stream>>>(Wl1, WlT1, 128, 512);
  transpose_f16_kernel<<<g, 256, 0, stream>>>(Wr1, WrT1, 128, 512);
  g = (512 * 512 + 255) / 256;
  transpose_f16_kernel<<<g, 256, 0, stream>>>(Wl2, WlT2, 512, 512);
  transpose_f16_kernel<<<g, 256, 0, stream>>>(Wr2, WrT2, 512, 512);
  transpose_f16_kernel<<<g, 256, 0, stream>>>(Wd1, WdT1, 512, 512);
  g = (512 * 64 + 255) / 256;
  transpose_f16_kernel<<<g, 256, 0, stream>>>(Wd2, WdT2, 512, 64);
  g = (16 * 512 + 255) / 256;
  transpose_f16_kernel<<<g, 256, 0, stream>>>(We1, WeP1, 16, 512);
  transpose_f16_kernel<<<g, 256, 0, stream>>>(We2, WeP2, 16, 512);

  dim3 gg((N + 127) / 128, 4), gb(256);
  gemm_f16<false, false><<<gg, gb, 0, stream>>>(x16, WlT1, bl1, xl16, N, 128, 512);
  gemm_f16<false, false><<<gg, gb, 0, stream>>>(x16, WrT1, br1, xr16, N, 128, 512);

  g = (E * 16 + 255) / 256; edge_hist_kernel<<<g, 256, 0, stream>>>(dst0, ea, deg, lsum, E);
  g = (N * 16 + 255) / 256; loop_norm16_kernel<<<g, 256, 0, stream>>>(lsum, deg, ea16 + (size_t)E * 16, N);
  scan_kernel<<<1, 1024, 0, stream>>>(deg, offs, N);
  g = (EP + 255) / 256;
  csr_fill_kernel<<<g, 256, 0, stream>>>(src0, dst0, offs, deg, cnt, csr2, E, N);

  const int FGRID = 1536;  // 6 blocks/CU via grid size alone (VGPR 76 fits 6 waves/SIMD)

  // ---- GAT layer 1 (fused logits+softmax+aggregate) ----
  gat_fused_kernel<<<FGRID, 256, 0, stream>>>(xl16, xr16, csr2, offs,
                                              ea16, WeP1, att1, bias1, h16, N);

  // ---- GAT layer 2 ----
  gemm_f16<false, false><<<gg, gb, 0, stream>>>(h16, WlT2, bl2, xl16, N, 512, 512);
  gemm_f16<false, false><<<gg, gb, 0, stream>>>(h16, WrT2, br2, xr16, N, 512, 512);
  gat_fused_kernel<<<FGRID, 256, 0, stream>>>(xl16, xr16, csr2, offs,
                                              ea16, WeP2, att2, bias2, h16, N);

  // ---- decoder ----
  gemm_f16<true, false><<<gg, gb, 0, stream>>>(h16, WdT1, bd1, t16, N, 512, 512);
  dim3 gd((N + 127) / 128, 1);
  gemm_f16<false, true><<<gd, gb, 0, stream>>>(t16, WdT2, bd2, d_out, N, 512, 64);
}

// Round 6
// 647.029 us; speedup vs baseline: 2.6542x; 1.0937x over previous
//
#include <hip/hip_runtime.h>
#include <hip/hip_fp16.h>

typedef _Float16 half8 __attribute__((ext_vector_type(8)));
typedef _Float16 half2v __attribute__((ext_vector_type(2)));
typedef float f32x4 __attribute__((ext_vector_type(4)));

#if __has_builtin(__builtin_amdgcn_fdot2)
#define FDOT2(a, b, c) __builtin_amdgcn_fdot2((a), (b), (c), false)
#else
static __device__ __forceinline__ float FDOT2(half2v a, half2v b, float c) {
  return (float)a[0] * (float)b[0] + (float)a[1] * (float)b[1] + c;
}
#endif
#define H2(v8, p) ((half2v){(v8)[2 * (p)], (v8)[2 * (p) + 1]})

// ---------------- small utility kernels ----------------

__global__ void to_f16_kernel(const float* __restrict__ A, _Float16* __restrict__ B, int n) {
  int i = blockIdx.x * 256 + threadIdx.x;
  if (i < n) B[i] = (_Float16)A[i];
}

// WT[n*K+k] = W[k*N+n]
__global__ void transpose_f16_kernel(const float* __restrict__ W, _Float16* __restrict__ WT, int K, int N) {
  int i = blockIdx.x * 256 + threadIdx.x;
  if (i >= K * N) return;
  int n = i / K, k = i - n * K;
  WT[i] = (_Float16)W[(size_t)k * N + n];
}

// merged transpose: WT[1024][K]; rows 0..511 from Wl[k][n], rows 512..1023 from Wr[k][n-512]
__global__ void transpose_pair_kernel(const float* __restrict__ Wl, const float* __restrict__ Wr,
                                      _Float16* __restrict__ WT, int K) {
  int i = blockIdx.x * 256 + threadIdx.x;
  if (i >= 1024 * K) return;
  int n = i / K, k = i - n * K;
  float v = (n < 512) ? Wl[(size_t)k * 512 + n] : Wr[(size_t)k * 512 + (n - 512)];
  WT[i] = (_Float16)v;
}

// in-degree histogram (int atomics only)
__global__ void deg_hist_kernel(const int* __restrict__ dst0, int* __restrict__ deg, int E) {
  int i = blockIdx.x * 256 + threadIdx.x;
  if (i < E) atomicAdd(&deg[dst0[i]], 1);
}

// exclusive scan of (deg[v]+1) -> offs[0..N], single block
__global__ __launch_bounds__(1024) void scan_kernel(const int* __restrict__ deg, int* __restrict__ offs, int N) {
  __shared__ int part[1024];
  int t = threadIdx.x;
  int chunk = (N + 1023) / 1024;
  int b = t * chunk, e = min(b + chunk, N);
  int s = 0;
  for (int i = b; i < e; i++) s += deg[i] + 1;
  part[t] = s;
  __syncthreads();
  for (int off = 1; off < 1024; off <<= 1) {
    int v = (t >= off) ? part[t - off] : 0;
    __syncthreads();
    part[t] += v;
    __syncthreads();
  }
  int run = (t == 0) ? 0 : part[t - 1];
  for (int i = b; i < e; i++) { offs[i] = run; run += deg[i] + 1; }
  if (t == 1023) offs[N] = part[1023];
}

// scatter (eid, src) pairs into CSR buckets; self-loop eid=E+v at slot offs[v]+deg[v]; +6 pad
__global__ void csr_fill_kernel(const int* __restrict__ src0, const int* __restrict__ dst0,
                                const int* __restrict__ offs, const int* __restrict__ deg,
                                int* __restrict__ cnt, int2* __restrict__ csr2, int E, int N) {
  int i = blockIdx.x * 256 + threadIdx.x;
  if (i == 0) {
    int EP = E + N;
#pragma unroll
    for (int p = 0; p < 6; p++) csr2[EP + p] = make_int2(0, 0);
  }
  if (i < E) {
    int d = dst0[i];
    int p = offs[d] + atomicAdd(&cnt[d], 1);
    csr2[p] = make_int2(i, src0[i]);
  } else if (i < E + N) {
    int v = i - E;
    int p = offs[v] + deg[v];
    csr2[p] = make_int2(E + v, v);
  }
}

// self-loop edge_attr = mean of incoming ea, written as f16 into ea16[E+v][k].
// thread (v,k): 16 threads of a node read ea[eid*16+k] -> 64B coalesced per edge.
__global__ void loop_attr16_kernel(const float* __restrict__ ea, const int2* __restrict__ csr2,
                                   const int* __restrict__ offs, const int* __restrict__ deg,
                                   _Float16* __restrict__ ea16_loop, int N) {
  int i = blockIdx.x * 256 + threadIdx.x;
  if (i >= N * 16) return;
  int v = i >> 4, k = i & 15;
  int b = offs[v], dg = deg[v];
  float s = 0.f;
  for (int j = 0; j < dg; j++) {
    int eid = csr2[b + j].x;
    s += ea[(size_t)eid * 16 + k];
  }
  ea16_loop[i] = (_Float16)(s / fmaxf((float)dg, 1.0f));
}

// ---------------- GEMM: C[M,Nfull] = A[M,K](f16) * BT[Nfull,K](f16) + bias ----------------
// bias split: col<512 -> biasA[col], else biasB[col-512] (for merged Wl|Wr output)
template <bool RELU, bool OUT_F32>
__global__ __launch_bounds__(256) void gemm_f16(const _Float16* __restrict__ A,
                                                const _Float16* __restrict__ BT,
                                                const float* __restrict__ biasA,
                                                const float* __restrict__ biasB,
                                                void* __restrict__ C,
                                                int M, int K, int Nfull, int ldc) {
  __shared__ _Float16 As[128 * 40];
  __shared__ _Float16 Bs[128 * 40];
  int t = threadIdx.x;
  int m0 = blockIdx.x * 128;
  int n0 = blockIdx.y * 128;
  int l = t & 63, w = t >> 6;
  int wm = w & 1, wn = w >> 1;
  int lr = l & 15, lq = l >> 4;

  f32x4 acc[4][4];
#pragma unroll
  for (int i = 0; i < 4; i++)
#pragma unroll
    for (int j = 0; j < 4; j++) acc[i][j] = (f32x4){0.f, 0.f, 0.f, 0.f};

  const half8 hzero = {0, 0, 0, 0, 0, 0, 0, 0};
  int srow = t >> 2;
  int sq = (t & 3) * 8;

  for (int kk = 0; kk < K; kk += 32) {
    half8 a0 = (m0 + srow < M) ? *(const half8*)(A + (size_t)(m0 + srow) * K + kk + sq) : hzero;
    half8 a1 = (m0 + srow + 64 < M) ? *(const half8*)(A + (size_t)(m0 + srow + 64) * K + kk + sq) : hzero;
    half8 b0 = (n0 + srow < Nfull) ? *(const half8*)(BT + (size_t)(n0 + srow) * K + kk + sq) : hzero;
    half8 b1 = (n0 + srow + 64 < Nfull) ? *(const half8*)(BT + (size_t)(n0 + srow + 64) * K + kk + sq) : hzero;
    __syncthreads();
    *(half8*)&As[srow * 40 + sq] = a0;
    *(half8*)&As[(srow + 64) * 40 + sq] = a1;
    *(half8*)&Bs[srow * 40 + sq] = b0;
    *(half8*)&Bs[(srow + 64) * 40 + sq] = b1;
    __syncthreads();
    half8 af[4], bf[4];
#pragma unroll
    for (int mi = 0; mi < 4; mi++) af[mi] = *(const half8*)&As[(wm * 64 + mi * 16 + lr) * 40 + lq * 8];
#pragma unroll
    for (int ni = 0; ni < 4; ni++) bf[ni] = *(const half8*)&Bs[(wn * 64 + ni * 16 + lr) * 40 + lq * 8];
#pragma unroll
    for (int mi = 0; mi < 4; mi++)
#pragma unroll
      for (int ni = 0; ni < 4; ni++)
        acc[mi][ni] = __builtin_amdgcn_mfma_f32_16x16x32_f16(af[mi], bf[ni], acc[mi][ni], 0, 0, 0);
  }

#pragma unroll
  for (int ni = 0; ni < 4; ni++) {
    int col = n0 + wn * 64 + ni * 16 + lr;
    if (col >= Nfull) continue;
    float bv = (col < 512) ? biasA[col] : biasB[col - 512];
#pragma unroll
    for (int mi = 0; mi < 4; mi++) {
#pragma unroll
      for (int r = 0; r < 4; r++) {
        int row = m0 + wm * 64 + mi * 16 + lq * 4 + r;
        if (row >= M) continue;
        float v = acc[mi][ni][r] + bv;
        if (RELU) v = fmaxf(v, 0.f);
        if (OUT_F32) ((float*)C)[(size_t)row * ldc + col] = v;
        else ((_Float16*)C)[(size_t)row * ldc + col] = (_Float16)v;
      }
    }
  }
}

// ---------------- fused GATv2 edge pass ----------------

__device__ __forceinline__ void edge_compute(
    half8 xs, half8 e0, half8 e1,
    const half8 Wf0[8], const half8 Wf1[8],
    const float attf[8], const float xrf[8],
    float& m, float& den, float acc[8]) {
  float xsf[8];
#pragma unroll
  for (int jj = 0; jj < 8; jj++) xsf[jj] = (float)xs[jj];
  float partial = 0.f;
#pragma unroll
  for (int jj = 0; jj < 8; jj++) {
    float ef = 0.f;
#pragma unroll
    for (int p = 0; p < 4; p++) ef = FDOT2(H2(e0, p), H2(Wf0[jj], p), ef);
#pragma unroll
    for (int p = 0; p < 4; p++) ef = FDOT2(H2(e1, p), H2(Wf1[jj], p), ef);
    float val = xsf[jj] + xrf[jj] + ef;
    val = val > 0.f ? val : 0.2f * val;
    partial = fmaf(val, attf[jj], partial);
  }
#pragma unroll
  for (int off2 = 1; off2 < 16; off2 <<= 1) partial += __shfl_xor(partial, off2);
  float mn = fmaxf(m, partial);
  float sc = __expf(m - mn);
  float al = __expf(partial - mn);
  den = den * sc + al;
#pragma unroll
  for (int jj = 0; jj < 8; jj++) acc[jj] = fmaf(acc[jj], sc, al * xsf[jj]);
  m = mn;
}

// wave per node, online softmax, depth-2 software pipeline (2 edges/iter).
// xlr is [N][1024]: cols 0..511 = xl (=Wl x + bl), cols 512..1023 = xr.
// NOTE: plain __launch_bounds__(256) — round 4 showed min-waves/EU makes the
// allocator spill the We fragments. Residency comes from grid size alone.
__global__ __launch_bounds__(256) void gat_fused_kernel(
    const _Float16* __restrict__ xlr,
    const int2* __restrict__ csr2, const int* __restrict__ offs,
    const _Float16* __restrict__ ea16,   // [E+N][16]
    const _Float16* __restrict__ WeP,    // [512][16]  (WeP[c][k] = We[k][c])
    const float* __restrict__ att, const float* __restrict__ bias,
    _Float16* __restrict__ hout, int N) {
  int l = threadIdx.x & 63;
  int h = l >> 4;
  int c0 = l * 8;

  half8 Wf0[8], Wf1[8];
#pragma unroll
  for (int j = 0; j < 8; j++) {
    Wf0[j] = *(const half8*)(WeP + (size_t)(c0 + j) * 16);
    Wf1[j] = *(const half8*)(WeP + (size_t)(c0 + j) * 16 + 8);
  }
  float attf[8];
  const float* attp = att + h * 128 + (l & 15) * 8;
#pragma unroll
  for (int j = 0; j < 8; j++) attf[j] = attp[j];

  int wid = blockIdx.x * 4 + (threadIdx.x >> 6);
  int nw = gridDim.x * 4;

  for (int v = wid; v < N; v += nw) {
    int b = offs[v], e2 = offs[v + 1];
    half8 xrv = *(const half8*)(xlr + (size_t)v * 1024 + 512 + c0);
    float xrf[8];
#pragma unroll
    for (int jj = 0; jj < 8; jj++) xrf[jj] = (float)xrv[jj];

    // preload edges b, b+1 into slots; resolve indices for b+2, b+3
    int2 i0 = csr2[b], i1 = csr2[b + 1];
    half8 xs0 = *(const half8*)(xlr + (size_t)i0.y * 1024 + c0);
    half8 e00 = *(const half8*)(ea16 + (size_t)i0.x * 16);
    half8 e01 = *(const half8*)(ea16 + (size_t)i0.x * 16 + 8);
    half8 xs1 = *(const half8*)(xlr + (size_t)i1.y * 1024 + c0);
    half8 e10 = *(const half8*)(ea16 + (size_t)i1.x * 16);
    half8 e11 = *(const half8*)(ea16 + (size_t)i1.x * 16 + 8);
    int2 n2 = csr2[b + 2], n3 = csr2[b + 3];

    float m = -1e30f, den = 0.f;
    float acc[8];
#pragma unroll
    for (int j = 0; j < 8; j++) acc[j] = 0.f;

    for (int j = b; j < e2; j += 2) {
      // snapshot current pair (waits on loads issued a full iteration ago)
      half8 axs = xs0, ae0 = e00, ae1 = e01;
      half8 bxs = xs1, be0 = e10, be1 = e11;
      // refill both slots for edges j+2, j+3 (in flight across both computes)
      xs0 = *(const half8*)(xlr + (size_t)n2.y * 1024 + c0);
      e00 = *(const half8*)(ea16 + (size_t)n2.x * 16);
      e01 = *(const half8*)(ea16 + (size_t)n2.x * 16 + 8);
      xs1 = *(const half8*)(xlr + (size_t)n3.y * 1024 + c0);
      e10 = *(const half8*)(ea16 + (size_t)n3.x * 16);
      e11 = *(const half8*)(ea16 + (size_t)n3.x * 16 + 8);
      n2 = csr2[j + 4]; n3 = csr2[j + 5];   // padded: safe

      edge_compute(axs, ae0, ae1, Wf0, Wf1, attf, xrf, m, den, acc);
      if (j + 1 < e2)
        edge_compute(bxs, be0, be1, Wf0, Wf1, attf, xrf, m, den, acc);
    }
    float rd = 1.f / (den + 1e-16f);
    half8 o;
#pragma unroll
    for (int jj = 0; jj < 8; jj++) o[jj] = (_Float16)(fmaf(acc[jj], rd, bias[c0 + jj]));
    *(half8*)(hout + (size_t)v * 512 + c0) = o;
  }
}

// ---------------- launcher ----------------

extern "C" void kernel_launch(void* const* d_in, const int* in_sizes, int n_in,
                              void* d_out, int out_size, void* d_ws, size_t ws_size,
                              hipStream_t stream) {
  (void)n_in; (void)out_size; (void)ws_size;
  const float* x    = (const float*)d_in[0];
  const int*   ei   = (const int*)d_in[1];
  const float* ea   = (const float*)d_in[2];
  const float* Wl1  = (const float*)d_in[3];
  const float* bl1  = (const float*)d_in[4];
  const float* Wr1  = (const float*)d_in[5];
  const float* br1  = (const float*)d_in[6];
  const float* We1  = (const float*)d_in[7];
  const float* att1 = (const float*)d_in[8];
  const float* bias1= (const float*)d_in[9];
  const float* Wl2  = (const float*)d_in[10];
  const float* bl2  = (const float*)d_in[11];
  const float* Wr2  = (const float*)d_in[12];
  const float* br2  = (const float*)d_in[13];
  const float* We2  = (const float*)d_in[14];
  const float* att2 = (const float*)d_in[15];
  const float* bias2= (const float*)d_in[16];
  const float* Wd1  = (const float*)d_in[17];
  const float* bd1  = (const float*)d_in[18];
  const float* Wd2  = (const float*)d_in[19];
  const float* bd2  = (const float*)d_in[20];

  const int N = in_sizes[0] / 128;
  const int E = in_sizes[1] / 2;
  const int EP = E + N;
  const int* src0 = ei;
  const int* dst0 = ei + E;

  char* ws = (char*)d_ws;
  size_t off = 0;
  auto alloc = [&](size_t bytes) -> void* {
    void* p = ws + off;
    off += (bytes + 255) & ~(size_t)255;
    return p;
  };

  // deg | cnt contiguous -> single memset
  int*   deg   = (int*)alloc((size_t)N * 8);
  int*   cnt   = deg + N;
  int*   offs  = (int*)alloc(((size_t)N + 1) * 4);
  int2*  csr2  = (int2*)alloc(((size_t)EP + 6) * 8);
  _Float16* ea16 = (_Float16*)alloc((size_t)EP * 16 * 2);
  _Float16* x16  = (_Float16*)alloc((size_t)N * 128 * 2);
  _Float16* xlr16= (_Float16*)alloc((size_t)N * 1024 * 2);
  _Float16* h16  = (_Float16*)alloc((size_t)N * 512 * 2);
  _Float16* WlrT1= (_Float16*)alloc(1024 * 128 * 2);
  _Float16* WlrT2= (_Float16*)alloc(1024 * 512 * 2);
  _Float16* WdT1 = (_Float16*)alloc(512 * 512 * 2);
  _Float16* WdT2 = (_Float16*)alloc(512 * 64 * 2);
  _Float16* WeP1 = (_Float16*)alloc(512 * 16 * 2);
  _Float16* WeP2 = (_Float16*)alloc(512 * 16 * 2);
  _Float16* t16  = xlr16;  // decoder hidden reuses xlr buffer (dead by then)

  hipMemsetAsync(deg, 0, (size_t)N * 8, stream);

  int g;
  g = (N * 128 + 255) / 256; to_f16_kernel<<<g, 256, 0, stream>>>(x, x16, N * 128);
  g = (E * 16 + 255) / 256;  to_f16_kernel<<<g, 256, 0, stream>>>(ea, ea16, E * 16);
  g = (1024 * 128 + 255) / 256;
  transpose_pair_kernel<<<g, 256, 0, stream>>>(Wl1, Wr1, WlrT1, 128);
  g = (1024 * 512 + 255) / 256;
  transpose_pair_kernel<<<g, 256, 0, stream>>>(Wl2, Wr2, WlrT2, 512);
  g = (512 * 512 + 255) / 256;
  transpose_f16_kernel<<<g, 256, 0, stream>>>(Wd1, WdT1, 512, 512);
  g = (512 * 64 + 255) / 256;
  transpose_f16_kernel<<<g, 256, 0, stream>>>(Wd2, WdT2, 512, 64);
  g = (16 * 512 + 255) / 256;
  transpose_f16_kernel<<<g, 256, 0, stream>>>(We1, WeP1, 16, 512);
  transpose_f16_kernel<<<g, 256, 0, stream>>>(We2, WeP2, 16, 512);

  // CSR build
  g = (E + 255) / 256;  deg_hist_kernel<<<g, 256, 0, stream>>>(dst0, deg, E);
  scan_kernel<<<1, 1024, 0, stream>>>(deg, offs, N);
  g = (EP + 255) / 256;
  csr_fill_kernel<<<g, 256, 0, stream>>>(src0, dst0, offs, deg, cnt, csr2, E, N);
  g = (N * 16 + 255) / 256;
  loop_attr16_kernel<<<g, 256, 0, stream>>>(ea, csr2, offs, deg, ea16 + (size_t)E * 16, N);

  dim3 gb(256);
  dim3 ggm((N + 127) / 128, 8);   // merged Wl|Wr: Nfull=1024
  dim3 ggd((N + 127) / 128, 4);   // decoder hidden: Nfull=512
  dim3 ggo((N + 127) / 128, 1);   // output: Nfull=64

  int FGRID = min(1536, (N + 15) / 16);  // N=20000 -> 1250 blocks = 5000 waves = exactly 4 nodes/wave

  // ---- GAT layer 1 ----
  gemm_f16<false, false><<<ggm, gb, 0, stream>>>(x16, WlrT1, bl1, br1, xlr16, N, 128, 1024, 1024);
  gat_fused_kernel<<<FGRID, 256, 0, stream>>>(xlr16, csr2, offs, ea16, WeP1, att1, bias1, h16, N);

  // ---- GAT layer 2 ----
  gemm_f16<false, false><<<ggm, gb, 0, stream>>>(h16, WlrT2, bl2, br2, xlr16, N, 512, 1024, 1024);
  gat_fused_kernel<<<FGRID, 256, 0, stream>>>(xlr16, csr2, offs, ea16, WeP2, att2, bias2, h16, N);

  // ---- decoder ----
  gemm_f16<true, false><<<ggd, gb, 0, stream>>>(h16, WdT1, bd1, bd1, t16, N, 512, 512, 512);
  gemm_f16<false, true><<<ggo, gb, 0, stream>>>(t16, WdT2, bd2, bd2, d_out, N, 512, 64, 64);
}

// Round 7
// 615.483 us; speedup vs baseline: 2.7902x; 1.0513x over previous
//
#include <hip/hip_runtime.h>
#include <hip/hip_fp16.h>

typedef _Float16 half8 __attribute__((ext_vector_type(8)));
typedef _Float16 half2v __attribute__((ext_vector_type(2)));
typedef float f32x4 __attribute__((ext_vector_type(4)));

#if __has_builtin(__builtin_amdgcn_fdot2)
#define FDOT2(a, b, c) __builtin_amdgcn_fdot2((a), (b), (c), false)
#else
static __device__ __forceinline__ float FDOT2(half2v a, half2v b, float c) {
  return (float)a[0] * (float)b[0] + (float)a[1] * (float)b[1] + c;
}
#endif
#define H2(v8, p) ((half2v){(v8)[2 * (p)], (v8)[2 * (p) + 1]})

// ---------------- mega prep kernel: x->f16 + all weight transposes ----------------
__global__ void prep_kernel(const float* __restrict__ x, _Float16* __restrict__ x16, int nx,
                            const float* __restrict__ Wl1, const float* __restrict__ Wr1,
                            _Float16* __restrict__ WlrT1,
                            const float* __restrict__ Wl2, const float* __restrict__ Wr2,
                            _Float16* __restrict__ WlrT2,
                            const float* __restrict__ Wd1, _Float16* __restrict__ WdT1,
                            const float* __restrict__ Wd2, _Float16* __restrict__ WdT2,
                            const float* __restrict__ We1, _Float16* __restrict__ WeP1,
                            const float* __restrict__ We2, _Float16* __restrict__ WeP2) {
  int i = blockIdx.x * 256 + threadIdx.x;
  if (i < nx) { x16[i] = (_Float16)x[i]; return; }
  i -= nx;
  if (i < 1024 * 128) {  // WlrT1[n][k], k<128
    int n = i >> 7, k = i & 127;
    float v = (n < 512) ? Wl1[(size_t)k * 512 + n] : Wr1[(size_t)k * 512 + (n - 512)];
    WlrT1[i] = (_Float16)v; return;
  }
  i -= 1024 * 128;
  if (i < 1024 * 512) {  // WlrT2[n][k], k<512
    int n = i >> 9, k = i & 511;
    float v = (n < 512) ? Wl2[(size_t)k * 512 + n] : Wr2[(size_t)k * 512 + (n - 512)];
    WlrT2[i] = (_Float16)v; return;
  }
  i -= 1024 * 512;
  if (i < 512 * 512) { int n = i >> 9, k = i & 511; WdT1[i] = (_Float16)Wd1[(size_t)k * 512 + n]; return; }
  i -= 512 * 512;
  if (i < 64 * 512)  { int n = i >> 9, k = i & 511; WdT2[i] = (_Float16)Wd2[(size_t)k * 64 + n]; return; }
  i -= 64 * 512;
  if (i < 512 * 16)  { int c = i >> 4, k = i & 15; WeP1[i] = (_Float16)We1[(size_t)k * 512 + c]; return; }
  i -= 512 * 16;
  if (i < 512 * 16)  { int c = i >> 4, k = i & 15; WeP2[i] = (_Float16)We2[(size_t)k * 512 + c]; return; }
}

// ---------------- CSR build ----------------
__global__ void deg_hist_kernel(const int* __restrict__ dst0, int* __restrict__ deg, int E) {
  int i = blockIdx.x * 256 + threadIdx.x;
  if (i < E) atomicAdd(&deg[dst0[i]], 1);
}

__global__ __launch_bounds__(1024) void scan_kernel(const int* __restrict__ deg, int* __restrict__ offs, int N) {
  __shared__ int part[1024];
  int t = threadIdx.x;
  int chunk = (N + 1023) / 1024;
  int b = t * chunk, e = min(b + chunk, N);
  int s = 0;
  for (int i = b; i < e; i++) s += deg[i] + 1;
  part[t] = s;
  __syncthreads();
  for (int off = 1; off < 1024; off <<= 1) {
    int v = (t >= off) ? part[t - off] : 0;
    __syncthreads();
    part[t] += v;
    __syncthreads();
  }
  int run = (t == 0) ? 0 : part[t - 1];
  for (int i = b; i < e; i++) { offs[i] = run; run += deg[i] + 1; }
  if (t == 1023) offs[N] = part[1023];
}

// separate src/eid arrays; +8 pad
__global__ void csr_fill_kernel(const int* __restrict__ src0, const int* __restrict__ dst0,
                                const int* __restrict__ offs, const int* __restrict__ deg,
                                int* __restrict__ cnt, int* __restrict__ csr_src,
                                int* __restrict__ csr_eid, int E, int N) {
  int i = blockIdx.x * 256 + threadIdx.x;
  if (i < 8) { csr_src[E + N + i] = 0; csr_eid[E + N + i] = 0; }
  if (i < E) {
    int d = dst0[i];
    int p = offs[d] + atomicAdd(&cnt[d], 1);
    csr_src[p] = src0[i];
    csr_eid[p] = i;
  } else if (i < E + N) {
    int v = i - E;
    int p = offs[v] + deg[v];
    csr_src[p] = v;
    csr_eid[p] = E + v;   // >=E marks self-loop; filled by loop_attr_kernel
  }
}

// gather ea (f32) into slot order as f16; skips self-loop slots
__global__ void ea_sort_kernel(const float* __restrict__ ea, const int* __restrict__ csr_eid,
                               _Float16* __restrict__ eas, int EP, int E) {
  int i = blockIdx.x * 256 + threadIdx.x;
  if (i >= EP * 16) return;
  int p = i >> 4, k = i & 15;
  int eid = csr_eid[p];
  if (eid < E) eas[i] = (_Float16)ea[(size_t)eid * 16 + k];
}

// self-loop attr = mean of real incoming slots (sequential f16 reads), written into its slot
__global__ void loop_attr_kernel(const int* __restrict__ offs, const int* __restrict__ deg,
                                 _Float16* __restrict__ eas, int N) {
  int i = blockIdx.x * 256 + threadIdx.x;
  if (i >= N * 16) return;
  int v = i >> 4, k = i & 15;
  int b = offs[v], dg = deg[v];
  float s = 0.f;
  for (int j = 0; j < dg; j++) s += (float)eas[((size_t)(b + j)) * 16 + k];
  eas[((size_t)(b + dg)) * 16 + k] = (_Float16)(s / fmaxf((float)dg, 1.0f));
}

// ---------------- GEMM: C[M,Nfull] = A[M,K](f16) * BT[Nfull,K](f16) + bias ----------------
template <bool RELU, bool OUT_F32>
__global__ __launch_bounds__(256) void gemm_f16(const _Float16* __restrict__ A,
                                                const _Float16* __restrict__ BT,
                                                const float* __restrict__ biasA,
                                                const float* __restrict__ biasB,
                                                void* __restrict__ C,
                                                int M, int K, int Nfull, int ldc) {
  __shared__ _Float16 As[128 * 40];
  __shared__ _Float16 Bs[128 * 40];
  int t = threadIdx.x;
  int m0 = blockIdx.x * 128;
  int n0 = blockIdx.y * 128;
  int l = t & 63, w = t >> 6;
  int wm = w & 1, wn = w >> 1;
  int lr = l & 15, lq = l >> 4;

  f32x4 acc[4][4];
#pragma unroll
  for (int i = 0; i < 4; i++)
#pragma unroll
    for (int j = 0; j < 4; j++) acc[i][j] = (f32x4){0.f, 0.f, 0.f, 0.f};

  const half8 hzero = {0, 0, 0, 0, 0, 0, 0, 0};
  int srow = t >> 2;
  int sq = (t & 3) * 8;

  for (int kk = 0; kk < K; kk += 32) {
    half8 a0 = (m0 + srow < M) ? *(const half8*)(A + (size_t)(m0 + srow) * K + kk + sq) : hzero;
    half8 a1 = (m0 + srow + 64 < M) ? *(const half8*)(A + (size_t)(m0 + srow + 64) * K + kk + sq) : hzero;
    half8 b0 = (n0 + srow < Nfull) ? *(const half8*)(BT + (size_t)(n0 + srow) * K + kk + sq) : hzero;
    half8 b1 = (n0 + srow + 64 < Nfull) ? *(const half8*)(BT + (size_t)(n0 + srow + 64) * K + kk + sq) : hzero;
    __syncthreads();
    *(half8*)&As[srow * 40 + sq] = a0;
    *(half8*)&As[(srow + 64) * 40 + sq] = a1;
    *(half8*)&Bs[srow * 40 + sq] = b0;
    *(half8*)&Bs[(srow + 64) * 40 + sq] = b1;
    __syncthreads();
    half8 af[4], bf[4];
#pragma unroll
    for (int mi = 0; mi < 4; mi++) af[mi] = *(const half8*)&As[(wm * 64 + mi * 16 + lr) * 40 + lq * 8];
#pragma unroll
    for (int ni = 0; ni < 4; ni++) bf[ni] = *(const half8*)&Bs[(wn * 64 + ni * 16 + lr) * 40 + lq * 8];
#pragma unroll
    for (int mi = 0; mi < 4; mi++)
#pragma unroll
      for (int ni = 0; ni < 4; ni++)
        acc[mi][ni] = __builtin_amdgcn_mfma_f32_16x16x32_f16(af[mi], bf[ni], acc[mi][ni], 0, 0, 0);
  }

#pragma unroll
  for (int ni = 0; ni < 4; ni++) {
    int col = n0 + wn * 64 + ni * 16 + lr;
    if (col >= Nfull) continue;
    float bv = (col < 512) ? biasA[col] : biasB[col - 512];
#pragma unroll
    for (int mi = 0; mi < 4; mi++) {
#pragma unroll
      for (int r = 0; r < 4; r++) {
        int row = m0 + wm * 64 + mi * 16 + lq * 4 + r;
        if (row >= M) continue;
        float v = acc[mi][ni][r] + bv;
        if (RELU) v = fmaxf(v, 0.f);
        if (OUT_F32) ((float*)C)[(size_t)row * ldc + col] = v;
        else ((_Float16*)C)[(size_t)row * ldc + col] = (_Float16)v;
      }
    }
  }
}

// ---------------- fused GATv2 edge pass ----------------

__device__ __forceinline__ void edge_compute(
    half8 xs, half8 e0, half8 e1,
    const half8 Wf0[8], const half8 Wf1[8],
    const float attf[8], const float xrf[8],
    float& m, float& den, float acc[8]) {
  float xsf[8];
#pragma unroll
  for (int jj = 0; jj < 8; jj++) xsf[jj] = (float)xs[jj];
  float partial = 0.f;
#pragma unroll
  for (int jj = 0; jj < 8; jj++) {
    float ef = xsf[jj] + xrf[jj];   // fold the z-sum into the dot accumulator
#pragma unroll
    for (int p = 0; p < 4; p++) ef = FDOT2(H2(e0, p), H2(Wf0[jj], p), ef);
#pragma unroll
    for (int p = 0; p < 4; p++) ef = FDOT2(H2(e1, p), H2(Wf1[jj], p), ef);
    float val = fmaxf(ef, 0.2f * ef);     // leaky relu, 2 inst
    partial = fmaf(val, attf[jj], partial);
  }
#pragma unroll
  for (int off2 = 1; off2 < 16; off2 <<= 1) partial += __shfl_xor(partial, off2);
  float mn = fmaxf(m, partial);
  float sc = __expf(m - mn);
  float al = __expf(partial - mn);
  den = den * sc + al;
#pragma unroll
  for (int jj = 0; jj < 8; jj++) acc[jj] = fmaf(acc[jj], sc, al * xsf[jj]);
  m = mn;
}

// wave per node, online softmax, 2-slot alternating pipeline (no snapshot copies).
// eas is slot-ordered: per-edge attr reads are sequential 32B, no eid indirection.
// Plain __launch_bounds__(256): min-waves/EU spills We fragments (round 4 evidence).
__global__ __launch_bounds__(256) void gat_fused_kernel(
    const _Float16* __restrict__ xlr,     // [N][1024]: 0..511 xl, 512..1023 xr
    const int* __restrict__ csr_src, const int* __restrict__ offs,
    const _Float16* __restrict__ eas,     // [EP+8][16] slot-ordered
    const _Float16* __restrict__ WeP,     // [512][16]
    const float* __restrict__ att, const float* __restrict__ bias,
    _Float16* __restrict__ hout, int N) {
  int l = threadIdx.x & 63;
  int h = l >> 4;
  int c0 = l * 8;

  half8 Wf0[8], Wf1[8];
#pragma unroll
  for (int j = 0; j < 8; j++) {
    Wf0[j] = *(const half8*)(WeP + (size_t)(c0 + j) * 16);
    Wf1[j] = *(const half8*)(WeP + (size_t)(c0 + j) * 16 + 8);
  }
  float attf[8];
  const float* attp = att + h * 128 + (l & 15) * 8;
#pragma unroll
  for (int j = 0; j < 8; j++) attf[j] = attp[j];

  int wid = blockIdx.x * 4 + (threadIdx.x >> 6);
  int nw = gridDim.x * 4;

  for (int v = wid; v < N; v += nw) {
    int b = offs[v], e2 = offs[v + 1];
    half8 xrv = *(const half8*)(xlr + (size_t)v * 1024 + 512 + c0);
    float xrf[8];
#pragma unroll
    for (int jj = 0; jj < 8; jj++) xrf[jj] = (float)xrv[jj];

    // prologue: slots hold edges b, b+1; src prefetched for b+2, b+3
    int s0 = csr_src[b], s1 = csr_src[b + 1];
    half8 xs0 = *(const half8*)(xlr + (size_t)s0 * 1024 + c0);
    half8 a00 = *(const half8*)(eas + (size_t)b * 16);
    half8 a01 = *(const half8*)(eas + (size_t)b * 16 + 8);
    half8 xs1 = *(const half8*)(xlr + (size_t)s1 * 1024 + c0);
    half8 a10 = *(const half8*)(eas + (size_t)(b + 1) * 16);
    half8 a11 = *(const half8*)(eas + (size_t)(b + 1) * 16 + 8);
    int s2 = csr_src[b + 2], s3 = csr_src[b + 3];

    float m = -1e30f, den = 0.f;
    float acc[8];
#pragma unroll
    for (int j = 0; j < 8; j++) acc[j] = 0.f;

    for (int j = b; j < e2; j += 2) {
      edge_compute(xs0, a00, a01, Wf0, Wf1, attf, xrf, m, den, acc);
      // refill slot 0 with edge j+2 (in flight across the next compute)
      xs0 = *(const half8*)(xlr + (size_t)s2 * 1024 + c0);
      a00 = *(const half8*)(eas + (size_t)(j + 2) * 16);
      a01 = *(const half8*)(eas + (size_t)(j + 2) * 16 + 8);
      s2 = csr_src[j + 4];            // padded: safe
      if (j + 1 < e2)
        edge_compute(xs1, a10, a11, Wf0, Wf1, attf, xrf, m, den, acc);
      // refill slot 1 with edge j+3
      xs1 = *(const half8*)(xlr + (size_t)s3 * 1024 + c0);
      a10 = *(const half8*)(eas + (size_t)(j + 3) * 16);
      a11 = *(const half8*)(eas + (size_t)(j + 3) * 16 + 8);
      s3 = csr_src[j + 5];            // padded: safe
    }
    float rd = 1.f / (den + 1e-16f);
    half8 o;
#pragma unroll
    for (int jj = 0; jj < 8; jj++) o[jj] = (_Float16)(fmaf(acc[jj], rd, bias[c0 + jj]));
    *(half8*)(hout + (size_t)v * 512 + c0) = o;
  }
}

// ---------------- launcher ----------------

extern "C" void kernel_launch(void* const* d_in, const int* in_sizes, int n_in,
                              void* d_out, int out_size, void* d_ws, size_t ws_size,
                              hipStream_t stream) {
  (void)n_in; (void)out_size; (void)ws_size;
  const float* x    = (const float*)d_in[0];
  const int*   ei   = (const int*)d_in[1];
  const float* ea   = (const float*)d_in[2];
  const float* Wl1  = (const float*)d_in[3];
  const float* bl1  = (const float*)d_in[4];
  const float* Wr1  = (const float*)d_in[5];
  const float* br1  = (const float*)d_in[6];
  const float* We1  = (const float*)d_in[7];
  const float* att1 = (const float*)d_in[8];
  const float* bias1= (const float*)d_in[9];
  const float* Wl2  = (const float*)d_in[10];
  const float* bl2  = (const float*)d_in[11];
  const float* Wr2  = (const float*)d_in[12];
  const float* br2  = (const float*)d_in[13];
  const float* We2  = (const float*)d_in[14];
  const float* att2 = (const float*)d_in[15];
  const float* bias2= (const float*)d_in[16];
  const float* Wd1  = (const float*)d_in[17];
  const float* bd1  = (const float*)d_in[18];
  const float* Wd2  = (const float*)d_in[19];
  const float* bd2  = (const float*)d_in[20];

  const int N = in_sizes[0] / 128;
  const int E = in_sizes[1] / 2;
  const int EP = E + N;
  const int* src0 = ei;
  const int* dst0 = ei + E;

  char* ws = (char*)d_ws;
  size_t off = 0;
  auto alloc = [&](size_t bytes) -> void* {
    void* p = ws + off;
    off += (bytes + 255) & ~(size_t)255;
    return p;
  };

  // deg | cnt contiguous -> single memset
  int*   deg    = (int*)alloc((size_t)N * 8);
  int*   cnt    = deg + N;
  int*   offs   = (int*)alloc(((size_t)N + 1) * 4);
  int*   csr_src= (int*)alloc(((size_t)EP + 8) * 4);
  int*   csr_eid= (int*)alloc(((size_t)EP + 8) * 4);
  _Float16* eas = (_Float16*)alloc(((size_t)EP + 8) * 16 * 2);
  _Float16* x16   = (_Float16*)alloc((size_t)N * 128 * 2);
  _Float16* xlr16 = (_Float16*)alloc((size_t)N * 1024 * 2);
  _Float16* h16   = (_Float16*)alloc((size_t)N * 512 * 2);
  _Float16* WlrT1 = (_Float16*)alloc(1024 * 128 * 2);
  _Float16* WlrT2 = (_Float16*)alloc(1024 * 512 * 2);
  _Float16* WdT1  = (_Float16*)alloc(512 * 512 * 2);
  _Float16* WdT2  = (_Float16*)alloc(64 * 512 * 2);
  _Float16* WeP1  = (_Float16*)alloc(512 * 16 * 2);
  _Float16* WeP2  = (_Float16*)alloc(512 * 16 * 2);
  _Float16* t16   = xlr16;  // decoder hidden reuses xlr buffer (dead by then)

  hipMemsetAsync(deg, 0, (size_t)N * 8, stream);

  // mega prep: x->f16 + all weight transposes in one launch
  int nx = N * 128;
  int prep_total = nx + 1024 * 128 + 1024 * 512 + 512 * 512 + 64 * 512 + 512 * 16 + 512 * 16;
  prep_kernel<<<(prep_total + 255) / 256, 256, 0, stream>>>(
      x, x16, nx, Wl1, Wr1, WlrT1, Wl2, Wr2, WlrT2,
      Wd1, WdT1, Wd2, WdT2, We1, WeP1, We2, WeP2);

  // CSR build + slot-ordered edge attrs
  int g;
  g = (E + 255) / 256;  deg_hist_kernel<<<g, 256, 0, stream>>>(dst0, deg, E);
  scan_kernel<<<1, 1024, 0, stream>>>(deg, offs, N);
  g = (EP + 255) / 256;
  csr_fill_kernel<<<g, 256, 0, stream>>>(src0, dst0, offs, deg, cnt, csr_src, csr_eid, E, N);
  g = (EP * 16 + 255) / 256;
  ea_sort_kernel<<<g, 256, 0, stream>>>(ea, csr_eid, eas, EP, E);
  g = (N * 16 + 255) / 256;
  loop_attr_kernel<<<g, 256, 0, stream>>>(offs, deg, eas, N);

  dim3 gb(256);
  dim3 ggm((N + 127) / 128, 8);   // merged Wl|Wr: Nfull=1024
  dim3 ggd((N + 127) / 128, 4);   // decoder hidden: Nfull=512
  dim3 ggo((N + 127) / 128, 1);   // output: Nfull=64

  const int FGRID = 1024;  // exact residency: 4 blocks/CU (VGPR 65..128 -> 4 waves/SIMD)

  // ---- GAT layer 1 ----
  gemm_f16<false, false><<<ggm, gb, 0, stream>>>(x16, WlrT1, bl1, br1, xlr16, N, 128, 1024, 1024);
  gat_fused_kernel<<<FGRID, 256, 0, stream>>>(xlr16, csr_src, offs, eas, WeP1, att1, bias1, h16, N);

  // ---- GAT layer 2 ----
  gemm_f16<false, false><<<ggm, gb, 0, stream>>>(h16, WlrT2, bl2, br2, xlr16, N, 512, 1024, 1024);
  gat_fused_kernel<<<FGRID, 256, 0, stream>>>(xlr16, csr_src, offs, eas, WeP2, att2, bias2, h16, N);

  // ---- decoder ----
  gemm_f16<true, false><<<ggd, gb, 0, stream>>>(h16, WdT1, bd1, bd1, t16, N, 512, 512, 512);
  gemm_f16<false, true><<<ggo, gb, 0, stream>>>(t16, WdT2, bd2, bd2, d_out, N, 512, 64, 64);
}

// Round 8
// 562.888 us; speedup vs baseline: 3.0509x; 1.0934x over previous
//
#include <hip/hip_runtime.h>
#include <hip/hip_fp16.h>

typedef _Float16 half8 __attribute__((ext_vector_type(8)));
typedef _Float16 half2v __attribute__((ext_vector_type(2)));
typedef float f32x4 __attribute__((ext_vector_type(4)));

#if __has_builtin(__builtin_amdgcn_fdot2)
#define FDOT2(a, b, c) __builtin_amdgcn_fdot2((a), (b), (c), false)
#else
static __device__ __forceinline__ float FDOT2(half2v a, half2v b, float c) {
  return (float)a[0] * (float)b[0] + (float)a[1] * (float)b[1] + c;
}
#endif
#define H2(v8, p) ((half2v){(v8)[2 * (p)], (v8)[2 * (p) + 1]})

// 16-lane all-reduce via DPP rotate-accumulate: 4 VALU ops, no LDS pipe.
// (round 7 evidence: ds_swizzle butterfly was a ~250cyc dependent LDS chain per edge)
template <int CTRL>
__device__ __forceinline__ float dpp_add16(float x) {
  int y = __builtin_amdgcn_update_dpp(0, __float_as_int(x), CTRL, 0xf, 0xf, true);
  return x + __int_as_float(y);
}
__device__ __forceinline__ float rowsum16(float x) {
  x = dpp_add16<0x128>(x);  // row_ror:8
  x = dpp_add16<0x124>(x);  // row_ror:4
  x = dpp_add16<0x122>(x);  // row_ror:2
  x = dpp_add16<0x121>(x);  // row_ror:1
  return x;                 // every lane of the 16-lane row holds the sum
}

// ---------------- mega prep kernel: x->f16 + all weight transposes ----------------
__global__ void prep_kernel(const float* __restrict__ x, _Float16* __restrict__ x16, int nx,
                            const float* __restrict__ Wl1, const float* __restrict__ Wr1,
                            _Float16* __restrict__ WlrT1,
                            const float* __restrict__ Wl2, const float* __restrict__ Wr2,
                            _Float16* __restrict__ WlrT2,
                            const float* __restrict__ Wd1, _Float16* __restrict__ WdT1,
                            const float* __restrict__ Wd2, _Float16* __restrict__ WdT2,
                            const float* __restrict__ We1, _Float16* __restrict__ WeP1,
                            const float* __restrict__ We2, _Float16* __restrict__ WeP2) {
  int i = blockIdx.x * 256 + threadIdx.x;
  if (i < nx) { x16[i] = (_Float16)x[i]; return; }
  i -= nx;
  if (i < 1024 * 128) {  // WlrT1[n][k], k<128
    int n = i >> 7, k = i & 127;
    float v = (n < 512) ? Wl1[(size_t)k * 512 + n] : Wr1[(size_t)k * 512 + (n - 512)];
    WlrT1[i] = (_Float16)v; return;
  }
  i -= 1024 * 128;
  if (i < 1024 * 512) {  // WlrT2[n][k], k<512
    int n = i >> 9, k = i & 511;
    float v = (n < 512) ? Wl2[(size_t)k * 512 + n] : Wr2[(size_t)k * 512 + (n - 512)];
    WlrT2[i] = (_Float16)v; return;
  }
  i -= 1024 * 512;
  if (i < 512 * 512) { int n = i >> 9, k = i & 511; WdT1[i] = (_Float16)Wd1[(size_t)k * 512 + n]; return; }
  i -= 512 * 512;
  if (i < 64 * 512)  { int n = i >> 9, k = i & 511; WdT2[i] = (_Float16)Wd2[(size_t)k * 64 + n]; return; }
  i -= 64 * 512;
  if (i < 512 * 16)  { int c = i >> 4, k = i & 15; WeP1[i] = (_Float16)We1[(size_t)k * 512 + c]; return; }
  i -= 512 * 16;
  if (i < 512 * 16)  { int c = i >> 4, k = i & 15; WeP2[i] = (_Float16)We2[(size_t)k * 512 + c]; return; }
}

// ---------------- CSR build ----------------
__global__ void deg_hist_kernel(const int* __restrict__ dst0, int* __restrict__ deg, int E) {
  int i = blockIdx.x * 256 + threadIdx.x;
  if (i < E) atomicAdd(&deg[dst0[i]], 1);
}

__global__ __launch_bounds__(1024) void scan_kernel(const int* __restrict__ deg, int* __restrict__ offs, int N) {
  __shared__ int part[1024];
  int t = threadIdx.x;
  int chunk = (N + 1023) / 1024;
  int b = t * chunk, e = min(b + chunk, N);
  int s = 0;
  for (int i = b; i < e; i++) s += deg[i] + 1;
  part[t] = s;
  __syncthreads();
  for (int off = 1; off < 1024; off <<= 1) {
    int v = (t >= off) ? part[t - off] : 0;
    __syncthreads();
    part[t] += v;
    __syncthreads();
  }
  int run = (t == 0) ? 0 : part[t - 1];
  for (int i = b; i < e; i++) { offs[i] = run; run += deg[i] + 1; }
  if (t == 1023) offs[N] = part[1023];
}

// separate src/eid arrays; +12 pad
__global__ void csr_fill_kernel(const int* __restrict__ src0, const int* __restrict__ dst0,
                                const int* __restrict__ offs, const int* __restrict__ deg,
                                int* __restrict__ cnt, int* __restrict__ csr_src,
                                int* __restrict__ csr_eid, int E, int N) {
  int i = blockIdx.x * 256 + threadIdx.x;
  if (i < 12) { csr_src[E + N + i] = 0; csr_eid[E + N + i] = 0; }
  if (i < E) {
    int d = dst0[i];
    int p = offs[d] + atomicAdd(&cnt[d], 1);
    csr_src[p] = src0[i];
    csr_eid[p] = i;
  } else if (i < E + N) {
    int v = i - E;
    int p = offs[v] + deg[v];
    csr_src[p] = v;
    csr_eid[p] = E + v;   // >=E marks self-loop; filled by loop_attr_kernel
  }
}

// gather ea (f32) into slot order as f16; skips self-loop slots
__global__ void ea_sort_kernel(const float* __restrict__ ea, const int* __restrict__ csr_eid,
                               _Float16* __restrict__ eas, int EP, int E) {
  int i = blockIdx.x * 256 + threadIdx.x;
  if (i >= EP * 16) return;
  int p = i >> 4, k = i & 15;
  int eid = csr_eid[p];
  if (eid < E) eas[i] = (_Float16)ea[(size_t)eid * 16 + k];
}

// self-loop attr = mean of real incoming slots (sequential f16 reads), written into its slot
__global__ void loop_attr_kernel(const int* __restrict__ offs, const int* __restrict__ deg,
                                 _Float16* __restrict__ eas, int N) {
  int i = blockIdx.x * 256 + threadIdx.x;
  if (i >= N * 16) return;
  int v = i >> 4, k = i & 15;
  int b = offs[v], dg = deg[v];
  float s = 0.f;
  for (int j = 0; j < dg; j++) s += (float)eas[((size_t)(b + j)) * 16 + k];
  eas[((size_t)(b + dg)) * 16 + k] = (_Float16)(s / fmaxf((float)dg, 1.0f));
}

// ---------------- GEMM: C[M,Nfull] = A[M,K](f16) * BT[Nfull,K](f16) + bias ----------------
template <bool RELU, bool OUT_F32>
__global__ __launch_bounds__(256) void gemm_f16(const _Float16* __restrict__ A,
                                                const _Float16* __restrict__ BT,
                                                const float* __restrict__ biasA,
                                                const float* __restrict__ biasB,
                                                void* __restrict__ C,
                                                int M, int K, int Nfull, int ldc) {
  __shared__ _Float16 As[128 * 40];
  __shared__ _Float16 Bs[128 * 40];
  int t = threadIdx.x;
  int m0 = blockIdx.x * 128;
  int n0 = blockIdx.y * 128;
  int l = t & 63, w = t >> 6;
  int wm = w & 1, wn = w >> 1;
  int lr = l & 15, lq = l >> 4;

  f32x4 acc[4][4];
#pragma unroll
  for (int i = 0; i < 4; i++)
#pragma unroll
    for (int j = 0; j < 4; j++) acc[i][j] = (f32x4){0.f, 0.f, 0.f, 0.f};

  const half8 hzero = {0, 0, 0, 0, 0, 0, 0, 0};
  int srow = t >> 2;
  int sq = (t & 3) * 8;

  for (int kk = 0; kk < K; kk += 32) {
    half8 a0 = (m0 + srow < M) ? *(const half8*)(A + (size_t)(m0 + srow) * K + kk + sq) : hzero;
    half8 a1 = (m0 + srow + 64 < M) ? *(const half8*)(A + (size_t)(m0 + srow + 64) * K + kk + sq) : hzero;
    half8 b0 = (n0 + srow < Nfull) ? *(const half8*)(BT + (size_t)(n0 + srow) * K + kk + sq) : hzero;
    half8 b1 = (n0 + srow + 64 < Nfull) ? *(const half8*)(BT + (size_t)(n0 + srow + 64) * K + kk + sq) : hzero;
    __syncthreads();
    *(half8*)&As[srow * 40 + sq] = a0;
    *(half8*)&As[(srow + 64) * 40 + sq] = a1;
    *(half8*)&Bs[srow * 40 + sq] = b0;
    *(half8*)&Bs[(srow + 64) * 40 + sq] = b1;
    __syncthreads();
    half8 af[4], bf[4];
#pragma unroll
    for (int mi = 0; mi < 4; mi++) af[mi] = *(const half8*)&As[(wm * 64 + mi * 16 + lr) * 40 + lq * 8];
#pragma unroll
    for (int ni = 0; ni < 4; ni++) bf[ni] = *(const half8*)&Bs[(wn * 64 + ni * 16 + lr) * 40 + lq * 8];
#pragma unroll
    for (int mi = 0; mi < 4; mi++)
#pragma unroll
      for (int ni = 0; ni < 4; ni++)
        acc[mi][ni] = __builtin_amdgcn_mfma_f32_16x16x32_f16(af[mi], bf[ni], acc[mi][ni], 0, 0, 0);
  }

#pragma unroll
  for (int ni = 0; ni < 4; ni++) {
    int col = n0 + wn * 64 + ni * 16 + lr;
    if (col >= Nfull) continue;
    float bv = (col < 512) ? biasA[col] : biasB[col - 512];
#pragma unroll
    for (int mi = 0; mi < 4; mi++) {
#pragma unroll
      for (int r = 0; r < 4; r++) {
        int row = m0 + wm * 64 + mi * 16 + lq * 4 + r;
        if (row >= M) continue;
        float v = acc[mi][ni][r] + bv;
        if (RELU) v = fmaxf(v, 0.f);
        if (OUT_F32) ((float*)C)[(size_t)row * ldc + col] = v;
        else ((_Float16*)C)[(size_t)row * ldc + col] = (_Float16)v;
      }
    }
  }
}

// ---------------- fused GATv2 edge pass ----------------

__device__ __forceinline__ void edge_compute(
    half8 xs, half8 e0, half8 e1,
    const half8 Wf0[8], const half8 Wf1[8],
    const float attf[8], const float xrf[8],
    float& m, float& den, float acc[8]) {
  float xsf[8];
#pragma unroll
  for (int jj = 0; jj < 8; jj++) xsf[jj] = (float)xs[jj];
  float partial = 0.f;
#pragma unroll
  for (int jj = 0; jj < 8; jj++) {
    float ef = xsf[jj] + xrf[jj];
#pragma unroll
    for (int p = 0; p < 4; p++) ef = FDOT2(H2(e0, p), H2(Wf0[jj], p), ef);
#pragma unroll
    for (int p = 0; p < 4; p++) ef = FDOT2(H2(e1, p), H2(Wf1[jj], p), ef);
    float val = fmaxf(ef, 0.2f * ef);
    partial = fmaf(val, attf[jj], partial);
  }
  partial = rowsum16(partial);   // DPP all-reduce (VALU), replaces ds_swizzle chain
  float mn = fmaxf(m, partial);
  float sc = __expf(m - mn);
  float al = __expf(partial - mn);
  den = den * sc + al;
#pragma unroll
  for (int jj = 0; jj < 8; jj++) acc[jj] = fmaf(acc[jj], sc, al * xsf[jj]);
  m = mn;
}

// wave per node, online softmax, 3-slot rotating pipeline (~2 edge-computes of
// load flight time). Plain __launch_bounds__(256): min-waves/EU spills the We
// fragments (round 4 evidence). Residency from grid size: 1024 = 4 blocks/CU.
__global__ __launch_bounds__(256) void gat_fused_kernel(
    const _Float16* __restrict__ xlr,     // [N][1024]: 0..511 xl, 512..1023 xr
    const int* __restrict__ csr_src, const int* __restrict__ offs,
    const _Float16* __restrict__ eas,     // [EP+12][16] slot-ordered
    const _Float16* __restrict__ WeP,     // [512][16]
    const float* __restrict__ att, const float* __restrict__ bias,
    _Float16* __restrict__ hout, int N) {
  int l = threadIdx.x & 63;
  int h = l >> 4;
  int c0 = l * 8;

  half8 Wf0[8], Wf1[8];
#pragma unroll
  for (int j = 0; j < 8; j++) {
    Wf0[j] = *(const half8*)(WeP + (size_t)(c0 + j) * 16);
    Wf1[j] = *(const half8*)(WeP + (size_t)(c0 + j) * 16 + 8);
  }
  float attf[8];
  const float* attp = att + h * 128 + (l & 15) * 8;
#pragma unroll
  for (int j = 0; j < 8; j++) attf[j] = attp[j];

  int wid = blockIdx.x * 4 + (threadIdx.x >> 6);
  int nw = gridDim.x * 4;

  for (int v = wid; v < N; v += nw) {
    int b = offs[v], e2 = offs[v + 1];
    half8 xrv = *(const half8*)(xlr + (size_t)v * 1024 + 512 + c0);
    float xrf[8];
#pragma unroll
    for (int jj = 0; jj < 8; jj++) xrf[jj] = (float)xrv[jj];

    // prologue: slots hold edges b, b+1, b+2; src prefetched for b+3..b+5
    int s0 = csr_src[b], s1 = csr_src[b + 1], s2 = csr_src[b + 2];
    half8 xs0 = *(const half8*)(xlr + (size_t)s0 * 1024 + c0);
    half8 a00 = *(const half8*)(eas + (size_t)b * 16);
    half8 a01 = *(const half8*)(eas + (size_t)b * 16 + 8);
    half8 xs1 = *(const half8*)(xlr + (size_t)s1 * 1024 + c0);
    half8 a10 = *(const half8*)(eas + (size_t)(b + 1) * 16);
    half8 a11 = *(const half8*)(eas + (size_t)(b + 1) * 16 + 8);
    half8 xs2 = *(const half8*)(xlr + (size_t)s2 * 1024 + c0);
    half8 a20 = *(const half8*)(eas + (size_t)(b + 2) * 16);
    half8 a21 = *(const half8*)(eas + (size_t)(b + 2) * 16 + 8);
    int s3 = csr_src[b + 3], s4 = csr_src[b + 4], s5 = csr_src[b + 5];

    float m = -1e30f, den = 0.f;
    float acc[8];
#pragma unroll
    for (int j = 0; j < 8; j++) acc[j] = 0.f;

    for (int j = b; j < e2; j += 3) {
      edge_compute(xs0, a00, a01, Wf0, Wf1, attf, xrf, m, den, acc);
      xs0 = *(const half8*)(xlr + (size_t)s3 * 1024 + c0);
      a00 = *(const half8*)(eas + (size_t)(j + 3) * 16);
      a01 = *(const half8*)(eas + (size_t)(j + 3) * 16 + 8);
      s3 = csr_src[j + 6];             // padded: safe
      if (j + 1 < e2)
        edge_compute(xs1, a10, a11, Wf0, Wf1, attf, xrf, m, den, acc);
      xs1 = *(const half8*)(xlr + (size_t)s4 * 1024 + c0);
      a10 = *(const half8*)(eas + (size_t)(j + 4) * 16);
      a11 = *(const half8*)(eas + (size_t)(j + 4) * 16 + 8);
      s4 = csr_src[j + 7];             // padded: safe
      if (j + 2 < e2)
        edge_compute(xs2, a20, a21, Wf0, Wf1, attf, xrf, m, den, acc);
      xs2 = *(const half8*)(xlr + (size_t)s5 * 1024 + c0);
      a20 = *(const half8*)(eas + (size_t)(j + 5) * 16);
      a21 = *(const half8*)(eas + (size_t)(j + 5) * 16 + 8);
      s5 = csr_src[j + 8];             // padded: safe
    }
    float rd = 1.f / (den + 1e-16f);
    half8 o;
#pragma unroll
    for (int jj = 0; jj < 8; jj++) o[jj] = (_Float16)(fmaf(acc[jj], rd, bias[c0 + jj]));
    *(half8*)(hout + (size_t)v * 512 + c0) = o;
  }
}

// ---------------- launcher ----------------

extern "C" void kernel_launch(void* const* d_in, const int* in_sizes, int n_in,
                              void* d_out, int out_size, void* d_ws, size_t ws_size,
                              hipStream_t stream) {
  (void)n_in; (void)out_size; (void)ws_size;
  const float* x    = (const float*)d_in[0];
  const int*   ei   = (const int*)d_in[1];
  const float* ea   = (const float*)d_in[2];
  const float* Wl1  = (const float*)d_in[3];
  const float* bl1  = (const float*)d_in[4];
  const float* Wr1  = (const float*)d_in[5];
  const float* br1  = (const float*)d_in[6];
  const float* We1  = (const float*)d_in[7];
  const float* att1 = (const float*)d_in[8];
  const float* bias1= (const float*)d_in[9];
  const float* Wl2  = (const float*)d_in[10];
  const float* bl2  = (const float*)d_in[11];
  const float* Wr2  = (const float*)d_in[12];
  const float* br2  = (const float*)d_in[13];
  const float* We2  = (const float*)d_in[14];
  const float* att2 = (const float*)d_in[15];
  const float* bias2= (const float*)d_in[16];
  const float* Wd1  = (const float*)d_in[17];
  const float* bd1  = (const float*)d_in[18];
  const float* Wd2  = (const float*)d_in[19];
  const float* bd2  = (const float*)d_in[20];

  const int N = in_sizes[0] / 128;
  const int E = in_sizes[1] / 2;
  const int EP = E + N;
  const int* src0 = ei;
  const int* dst0 = ei + E;

  char* ws = (char*)d_ws;
  size_t off = 0;
  auto alloc = [&](size_t bytes) -> void* {
    void* p = ws + off;
    off += (bytes + 255) & ~(size_t)255;
    return p;
  };

  // deg | cnt contiguous -> single memset
  int*   deg    = (int*)alloc((size_t)N * 8);
  int*   cnt    = deg + N;
  int*   offs   = (int*)alloc(((size_t)N + 1) * 4);
  int*   csr_src= (int*)alloc(((size_t)EP + 12) * 4);
  int*   csr_eid= (int*)alloc(((size_t)EP + 12) * 4);
  _Float16* eas = (_Float16*)alloc(((size_t)EP + 12) * 16 * 2);
  _Float16* x16   = (_Float16*)alloc((size_t)N * 128 * 2);
  _Float16* xlr16 = (_Float16*)alloc((size_t)N * 1024 * 2);
  _Float16* h16   = (_Float16*)alloc((size_t)N * 512 * 2);
  _Float16* WlrT1 = (_Float16*)alloc(1024 * 128 * 2);
  _Float16* WlrT2 = (_Float16*)alloc(1024 * 512 * 2);
  _Float16* WdT1  = (_Float16*)alloc(512 * 512 * 2);
  _Float16* WdT2  = (_Float16*)alloc(64 * 512 * 2);
  _Float16* WeP1  = (_Float16*)alloc(512 * 16 * 2);
  _Float16* WeP2  = (_Float16*)alloc(512 * 16 * 2);
  _Float16* t16   = xlr16;  // decoder hidden reuses xlr buffer (dead by then)

  hipMemsetAsync(deg, 0, (size_t)N * 8, stream);

  // mega prep: x->f16 + all weight transposes in one launch
  int nx = N * 128;
  int prep_total = nx + 1024 * 128 + 1024 * 512 + 512 * 512 + 64 * 512 + 512 * 16 + 512 * 16;
  prep_kernel<<<(prep_total + 255) / 256, 256, 0, stream>>>(
      x, x16, nx, Wl1, Wr1, WlrT1, Wl2, Wr2, WlrT2,
      Wd1, WdT1, Wd2, WdT2, We1, WeP1, We2, WeP2);

  // CSR build + slot-ordered edge attrs
  int g;
  g = (E + 255) / 256;  deg_hist_kernel<<<g, 256, 0, stream>>>(dst0, deg, E);
  scan_kernel<<<1, 1024, 0, stream>>>(deg, offs, N);
  g = (EP + 255) / 256;
  csr_fill_kernel<<<g, 256, 0, stream>>>(src0, dst0, offs, deg, cnt, csr_src, csr_eid, E, N);
  g = (EP * 16 + 255) / 256;
  ea_sort_kernel<<<g, 256, 0, stream>>>(ea, csr_eid, eas, EP, E);
  g = (N * 16 + 255) / 256;
  loop_attr_kernel<<<g, 256, 0, stream>>>(offs, deg, eas, N);

  dim3 gb(256);
  dim3 ggm((N + 127) / 128, 8);   // merged Wl|Wr: Nfull=1024
  dim3 ggd((N + 127) / 128, 4);   // decoder hidden: Nfull=512
  dim3 ggo((N + 127) / 128, 1);   // output: Nfull=64

  const int FGRID = 1024;  // exact residency: 4 blocks/CU (VGPR 65..128 -> 4 waves/SIMD)

  // ---- GAT layer 1 ----
  gemm_f16<false, false><<<ggm, gb, 0, stream>>>(x16, WlrT1, bl1, br1, xlr16, N, 128, 1024, 1024);
  gat_fused_kernel<<<FGRID, 256, 0, stream>>>(xlr16, csr_src, offs, eas, WeP1, att1, bias1, h16, N);

  // ---- GAT layer 2 ----
  gemm_f16<false, false><<<ggm, gb, 0, stream>>>(h16, WlrT2, bl2, br2, xlr16, N, 512, 1024, 1024);
  gat_fused_kernel<<<FGRID, 256, 0, stream>>>(xlr16, csr_src, offs, eas, WeP2, att2, bias2, h16, N);

  // ---- decoder ----
  gemm_f16<true, false><<<ggd, gb, 0, stream>>>(h16, WdT1, bd1, bd1, t16, N, 512, 512, 512);
  gemm_f16<false, true><<<ggo, gb, 0, stream>>>(t16, WdT2, bd2, bd2, d_out, N, 512, 64, 64);
}

// Round 9
// 553.428 us; speedup vs baseline: 3.1031x; 1.0171x over previous
//
#include <hip/hip_runtime.h>
#include <hip/hip_fp16.h>

typedef _Float16 half8 __attribute__((ext_vector_type(8)));
typedef _Float16 half2v __attribute__((ext_vector_type(2)));
typedef float f32x4 __attribute__((ext_vector_type(4)));

#if __has_builtin(__builtin_amdgcn_fdot2)
#define FDOT2(a, b, c) __builtin_amdgcn_fdot2((a), (b), (c), false)
#else
static __device__ __forceinline__ float FDOT2(half2v a, half2v b, float c) {
  return (float)a[0] * (float)b[0] + (float)a[1] * (float)b[1] + c;
}
#endif
#define H2(v8, p) ((half2v){(v8)[2 * (p)], (v8)[2 * (p) + 1]})

// async global->LDS, 16B per lane; dest = lds base (wave-uniform) + lane*16
#define GLOAD_LDS16(gp, lp)                                                        \
  __builtin_amdgcn_global_load_lds(                                                \
      (const __attribute__((address_space(1))) void*)(gp),                         \
      (__attribute__((address_space(3))) void*)(lp), 16, 0, 0)

// 16-lane all-reduce via DPP rotate-accumulate: 4 VALU ops, no LDS pipe.
template <int CTRL>
__device__ __forceinline__ float dpp_add16(float x) {
  int y = __builtin_amdgcn_update_dpp(0, __float_as_int(x), CTRL, 0xf, 0xf, true);
  return x + __int_as_float(y);
}
__device__ __forceinline__ float rowsum16(float x) {
  x = dpp_add16<0x128>(x);  // row_ror:8
  x = dpp_add16<0x124>(x);  // row_ror:4
  x = dpp_add16<0x122>(x);  // row_ror:2
  x = dpp_add16<0x121>(x);  // row_ror:1
  return x;
}

// ---------------- mega prep kernel: x->f16 + all weight transposes ----------------
__global__ void prep_kernel(const float* __restrict__ x, _Float16* __restrict__ x16, int nx,
                            const float* __restrict__ Wl1, const float* __restrict__ Wr1,
                            _Float16* __restrict__ WlrT1,
                            const float* __restrict__ Wl2, const float* __restrict__ Wr2,
                            _Float16* __restrict__ WlrT2,
                            const float* __restrict__ Wd1, _Float16* __restrict__ WdT1,
                            const float* __restrict__ Wd2, _Float16* __restrict__ WdT2,
                            const float* __restrict__ We1, _Float16* __restrict__ WeP1,
                            const float* __restrict__ We2, _Float16* __restrict__ WeP2) {
  int i = blockIdx.x * 256 + threadIdx.x;
  if (i < nx) { x16[i] = (_Float16)x[i]; return; }
  i -= nx;
  if (i < 1024 * 128) {
    int n = i >> 7, k = i & 127;
    float v = (n < 512) ? Wl1[(size_t)k * 512 + n] : Wr1[(size_t)k * 512 + (n - 512)];
    WlrT1[i] = (_Float16)v; return;
  }
  i -= 1024 * 128;
  if (i < 1024 * 512) {
    int n = i >> 9, k = i & 511;
    float v = (n < 512) ? Wl2[(size_t)k * 512 + n] : Wr2[(size_t)k * 512 + (n - 512)];
    WlrT2[i] = (_Float16)v; return;
  }
  i -= 1024 * 512;
  if (i < 512 * 512) { int n = i >> 9, k = i & 511; WdT1[i] = (_Float16)Wd1[(size_t)k * 512 + n]; return; }
  i -= 512 * 512;
  if (i < 64 * 512)  { int n = i >> 9, k = i & 511; WdT2[i] = (_Float16)Wd2[(size_t)k * 64 + n]; return; }
  i -= 64 * 512;
  if (i < 512 * 16)  { int c = i >> 4, k = i & 15; WeP1[i] = (_Float16)We1[(size_t)k * 512 + c]; return; }
  i -= 512 * 16;
  if (i < 512 * 16)  { int c = i >> 4, k = i & 15; WeP2[i] = (_Float16)We2[(size_t)k * 512 + c]; return; }
}

// ---------------- CSR build ----------------
__global__ void deg_hist_kernel(const int* __restrict__ dst0, int* __restrict__ deg, int E) {
  int i = blockIdx.x * 256 + threadIdx.x;
  if (i < E) atomicAdd(&deg[dst0[i]], 1);
}

__global__ __launch_bounds__(1024) void scan_kernel(const int* __restrict__ deg, int* __restrict__ offs, int N) {
  __shared__ int part[1024];
  int t = threadIdx.x;
  int chunk = (N + 1023) / 1024;
  int b = t * chunk, e = min(b + chunk, N);
  int s = 0;
  for (int i = b; i < e; i++) s += deg[i] + 1;
  part[t] = s;
  __syncthreads();
  for (int off = 1; off < 1024; off <<= 1) {
    int v = (t >= off) ? part[t - off] : 0;
    __syncthreads();
    part[t] += v;
    __syncthreads();
  }
  int run = (t == 0) ? 0 : part[t - 1];
  for (int i = b; i < e; i++) { offs[i] = run; run += deg[i] + 1; }
  if (t == 1023) offs[N] = part[1023];
}

// scatter src + slot-ordered edge attr (f16) in one pass; self-loop slot marked, +12 pad
__global__ void csr_fill_kernel(const int* __restrict__ src0, const int* __restrict__ dst0,
                                const float* __restrict__ ea,
                                const int* __restrict__ offs, const int* __restrict__ deg,
                                int* __restrict__ cnt, int* __restrict__ csr_src,
                                _Float16* __restrict__ eas, int E, int N) {
  int i = blockIdx.x * 256 + threadIdx.x;
  if (i < 12) {
    csr_src[E + N + i] = 0;
#pragma unroll
    for (int k = 0; k < 16; k++) eas[(size_t)(E + N + i) * 16 + k] = (_Float16)0.f;
  }
  if (i < E) {
    int d = dst0[i];
    int p = offs[d] + atomicAdd(&cnt[d], 1);
    csr_src[p] = src0[i];
    const float* s = ea + (size_t)i * 16;
    half8 h0, h1;
#pragma unroll
    for (int k = 0; k < 8; k++) { h0[k] = (_Float16)s[k]; h1[k] = (_Float16)s[k + 8]; }
    *(half8*)(eas + (size_t)p * 16) = h0;
    *(half8*)(eas + (size_t)p * 16 + 8) = h1;
  } else if (i < E + N) {
    int v = i - E;
    csr_src[offs[v] + deg[v]] = v;  // self-loop; attrs filled by loop_attr_kernel
  }
}

// self-loop attr = mean of real incoming slots (sequential f16 reads), written into its slot
__global__ void loop_attr_kernel(const int* __restrict__ offs, const int* __restrict__ deg,
                                 _Float16* __restrict__ eas, int N) {
  int i = blockIdx.x * 256 + threadIdx.x;
  if (i >= N * 16) return;
  int v = i >> 4, k = i & 15;
  int b = offs[v], dg = deg[v];
  float s = 0.f;
  for (int j = 0; j < dg; j++) s += (float)eas[((size_t)(b + j)) * 16 + k];
  eas[((size_t)(b + dg)) * 16 + k] = (_Float16)(s / fmaxf((float)dg, 1.0f));
}

// ---------------- GEMM: C[M,Nfull] = A[M,K](f16) * BT[Nfull,K](f16) + bias ----------------
// m97-style staging: global_load_lds dwordx4, contiguous [128][32]-half LDS tiles (no pad —
// DMA dest is wave-uniform base + lane*16). A/BT buffers MUST be padded to 128-row multiples.
template <bool RELU, bool OUT_F32>
__global__ __launch_bounds__(256) void gemm_f16(const _Float16* __restrict__ A,
                                                const _Float16* __restrict__ BT,
                                                const float* __restrict__ biasA,
                                                const float* __restrict__ biasB,
                                                void* __restrict__ C,
                                                int M, int K, int Nfull, int ldc) {
  __shared__ _Float16 As[128 * 32];
  __shared__ _Float16 Bs[128 * 32];
  int t = threadIdx.x;
  int m0 = blockIdx.x * 128;
  int n0 = blockIdx.y * 128;
  int l = t & 63, w = t >> 6;
  int wm = w & 1, wn = w >> 1;
  int lr = l & 15, lq = l >> 4;

  f32x4 acc[4][4];
#pragma unroll
  for (int i = 0; i < 4; i++)
#pragma unroll
    for (int j = 0; j < 4; j++) acc[i][j] = (f32x4){0.f, 0.f, 0.f, 0.f};

  // staging: wave w covers rows [w*32, w*32+32); lane i -> row w*32+i/4, halves (i%4)*8
  int r0 = w * 32 + (l >> 2);
  int cb = (l & 3) * 8;
  const _Float16* Ap = A + (size_t)(m0 + r0) * K + cb;
  const _Float16* Bp = BT + (size_t)(n0 + r0) * K + cb;
  _Float16* AsW = As + w * 32 * 32;   // wave-uniform LDS bases
  _Float16* BsW = Bs + w * 32 * 32;

  for (int kk = 0; kk < K; kk += 32) {
    GLOAD_LDS16(Ap, AsW);
    GLOAD_LDS16(Ap + (size_t)16 * K, AsW + 16 * 32);
    GLOAD_LDS16(Bp, BsW);
    GLOAD_LDS16(Bp + (size_t)16 * K, BsW + 16 * 32);
    Ap += 32; Bp += 32;
    __syncthreads();
    half8 af[4], bf[4];
#pragma unroll
    for (int mi = 0; mi < 4; mi++) af[mi] = *(const half8*)&As[(wm * 64 + mi * 16 + lr) * 32 + lq * 8];
#pragma unroll
    for (int ni = 0; ni < 4; ni++) bf[ni] = *(const half8*)&Bs[(wn * 64 + ni * 16 + lr) * 32 + lq * 8];
#pragma unroll
    for (int mi = 0; mi < 4; mi++)
#pragma unroll
      for (int ni = 0; ni < 4; ni++)
        acc[mi][ni] = __builtin_amdgcn_mfma_f32_16x16x32_f16(af[mi], bf[ni], acc[mi][ni], 0, 0, 0);
    __syncthreads();
  }

#pragma unroll
  for (int ni = 0; ni < 4; ni++) {
    int col = n0 + wn * 64 + ni * 16 + lr;
    if (col >= Nfull) continue;
    float bv = (col < 512) ? biasA[col] : biasB[col - 512];
#pragma unroll
    for (int mi = 0; mi < 4; mi++) {
#pragma unroll
      for (int r = 0; r < 4; r++) {
        int row = m0 + wm * 64 + mi * 16 + lq * 4 + r;
        if (row >= M) continue;
        float v = acc[mi][ni][r] + bv;
        if (RELU) v = fmaxf(v, 0.f);
        if (OUT_F32) ((float*)C)[(size_t)row * ldc + col] = v;
        else ((_Float16*)C)[(size_t)row * ldc + col] = (_Float16)v;
      }
    }
  }
}

// ---------------- fused GATv2 edge pass ----------------

__device__ __forceinline__ void edge_compute(
    half8 xs, half8 e0, half8 e1,
    const half8 Wf0[8], const half8 Wf1[8],
    const float attf[8], const float xrf[8],
    float& m, float& den, float acc[8]) {
  float xsf[8];
#pragma unroll
  for (int jj = 0; jj < 8; jj++) xsf[jj] = (float)xs[jj];
  float partial = 0.f;
#pragma unroll
  for (int jj = 0; jj < 8; jj++) {
    float ef = xsf[jj] + xrf[jj];
#pragma unroll
    for (int p = 0; p < 4; p++) ef = FDOT2(H2(e0, p), H2(Wf0[jj], p), ef);
#pragma unroll
    for (int p = 0; p < 4; p++) ef = FDOT2(H2(e1, p), H2(Wf1[jj], p), ef);
    float val = fmaxf(ef, 0.2f * ef);
    partial = fmaf(val, attf[jj], partial);
  }
  partial = rowsum16(partial);
  float mn = fmaxf(m, partial);
  float sc = __expf(m - mn);
  float al = __expf(partial - mn);
  den = den * sc + al;
#pragma unroll
  for (int jj = 0; jj < 8; jj++) acc[jj] = fmaf(acc[jj], sc, al * xsf[jj]);
  m = mn;
}

// wave per node, online softmax, 3-slot rotating pipeline. Node index forced
// uniform via readfirstlane so offs/csr_src/eas loads (wave-uniform addresses,
// never written here) can compile to s_load on the scalar pipe.
__global__ __launch_bounds__(256) void gat_fused_kernel(
    const _Float16* __restrict__ xlr,     // [Npad][1024]: 0..511 xl, 512..1023 xr
    const int* __restrict__ csr_src, const int* __restrict__ offs,
    const _Float16* __restrict__ eas,     // [EP+12][16] slot-ordered
    const _Float16* __restrict__ WeP,     // [512][16]
    const float* __restrict__ att, const float* __restrict__ bias,
    _Float16* __restrict__ hout, int N) {
  int l = threadIdx.x & 63;
  int h = l >> 4;
  int c0 = l * 8;

  half8 Wf0[8], Wf1[8];
#pragma unroll
  for (int j = 0; j < 8; j++) {
    Wf0[j] = *(const half8*)(WeP + (size_t)(c0 + j) * 16);
    Wf1[j] = *(const half8*)(WeP + (size_t)(c0 + j) * 16 + 8);
  }
  float attf[8];
  const float* attp = att + h * 128 + (l & 15) * 8;
#pragma unroll
  for (int j = 0; j < 8; j++) attf[j] = attp[j];

  int wid = blockIdx.x * 4 + (threadIdx.x >> 6);
  int nw = gridDim.x * 4;

  for (int v0 = wid; v0 < N; v0 += nw) {
    int v = __builtin_amdgcn_readfirstlane(v0);   // wave-uniform in SGPR
    int b = offs[v], e2 = offs[v + 1];
    half8 xrv = *(const half8*)(xlr + (size_t)v * 1024 + 512 + c0);
    float xrf[8];
#pragma unroll
    for (int jj = 0; jj < 8; jj++) xrf[jj] = (float)xrv[jj];

    int s0 = csr_src[b], s1 = csr_src[b + 1], s2 = csr_src[b + 2];
    half8 xs0 = *(const half8*)(xlr + (size_t)s0 * 1024 + c0);
    half8 a00 = *(const half8*)(eas + (size_t)b * 16);
    half8 a01 = *(const half8*)(eas + (size_t)b * 16 + 8);
    half8 xs1 = *(const half8*)(xlr + (size_t)s1 * 1024 + c0);
    half8 a10 = *(const half8*)(eas + (size_t)(b + 1) * 16);
    half8 a11 = *(const half8*)(eas + (size_t)(b + 1) * 16 + 8);
    half8 xs2 = *(const half8*)(xlr + (size_t)s2 * 1024 + c0);
    half8 a20 = *(const half8*)(eas + (size_t)(b + 2) * 16);
    half8 a21 = *(const half8*)(eas + (size_t)(b + 2) * 16 + 8);
    int s3 = csr_src[b + 3], s4 = csr_src[b + 4], s5 = csr_src[b + 5];

    float m = -1e30f, den = 0.f;
    float acc[8];
#pragma unroll
    for (int j = 0; j < 8; j++) acc[j] = 0.f;

    for (int j = b; j < e2; j += 3) {
      edge_compute(xs0, a00, a01, Wf0, Wf1, attf, xrf, m, den, acc);
      xs0 = *(const half8*)(xlr + (size_t)s3 * 1024 + c0);
      a00 = *(const half8*)(eas + (size_t)(j + 3) * 16);
      a01 = *(const half8*)(eas + (size_t)(j + 3) * 16 + 8);
      s3 = csr_src[j + 6];
      if (j + 1 < e2)
        edge_compute(xs1, a10, a11, Wf0, Wf1, attf, xrf, m, den, acc);
      xs1 = *(const half8*)(xlr + (size_t)s4 * 1024 + c0);
      a10 = *(const half8*)(eas + (size_t)(j + 4) * 16);
      a11 = *(const half8*)(eas + (size_t)(j + 4) * 16 + 8);
      s4 = csr_src[j + 7];
      if (j + 2 < e2)
        edge_compute(xs2, a20, a21, Wf0, Wf1, attf, xrf, m, den, acc);
      xs2 = *(const half8*)(xlr + (size_t)s5 * 1024 + c0);
      a20 = *(const half8*)(eas + (size_t)(j + 5) * 16);
      a21 = *(const half8*)(eas + (size_t)(j + 5) * 16 + 8);
      s5 = csr_src[j + 8];
    }
    float rd = 1.f / (den + 1e-16f);
    half8 o;
#pragma unroll
    for (int jj = 0; jj < 8; jj++) o[jj] = (_Float16)(fmaf(acc[jj], rd, bias[c0 + jj]));
    *(half8*)(hout + (size_t)v * 512 + c0) = o;
  }
}

// ---------------- launcher ----------------

extern "C" void kernel_launch(void* const* d_in, const int* in_sizes, int n_in,
                              void* d_out, int out_size, void* d_ws, size_t ws_size,
                              hipStream_t stream) {
  (void)n_in; (void)out_size; (void)ws_size;
  const float* x    = (const float*)d_in[0];
  const int*   ei   = (const int*)d_in[1];
  const float* ea   = (const float*)d_in[2];
  const float* Wl1  = (const float*)d_in[3];
  const float* bl1  = (const float*)d_in[4];
  const float* Wr1  = (const float*)d_in[5];
  const float* br1  = (const float*)d_in[6];
  const float* We1  = (const float*)d_in[7];
  const float* att1 = (const float*)d_in[8];
  const float* bias1= (const float*)d_in[9];
  const float* Wl2  = (const float*)d_in[10];
  const float* bl2  = (const float*)d_in[11];
  const float* Wr2  = (const float*)d_in[12];
  const float* br2  = (const float*)d_in[13];
  const float* We2  = (const float*)d_in[14];
  const float* att2 = (const float*)d_in[15];
  const float* bias2= (const float*)d_in[16];
  const float* Wd1  = (const float*)d_in[17];
  const float* bd1  = (const float*)d_in[18];
  const float* Wd2  = (const float*)d_in[19];
  const float* bd2  = (const float*)d_in[20];

  const int N = in_sizes[0] / 128;
  const int E = in_sizes[1] / 2;
  const int EP = E + N;
  const int Npad = (N + 127) & ~127;   // staging reads are unguarded -> pad row buffers
  const int* src0 = ei;
  const int* dst0 = ei + E;

  char* ws = (char*)d_ws;
  size_t off = 0;
  auto alloc = [&](size_t bytes) -> void* {
    void* p = ws + off;
    off += (bytes + 255) & ~(size_t)255;
    return p;
  };

  int*   deg    = (int*)alloc((size_t)N * 8);
  int*   cnt    = deg + N;
  int*   offs   = (int*)alloc(((size_t)N + 1) * 4);
  int*   csr_src= (int*)alloc(((size_t)EP + 12) * 4);
  _Float16* eas = (_Float16*)alloc(((size_t)EP + 12) * 16 * 2);
  _Float16* x16   = (_Float16*)alloc((size_t)Npad * 128 * 2);
  _Float16* xlr16 = (_Float16*)alloc((size_t)Npad * 1024 * 2);
  _Float16* h16   = (_Float16*)alloc((size_t)Npad * 512 * 2);
  _Float16* WlrT1 = (_Float16*)alloc(1024 * 128 * 2);
  _Float16* WlrT2 = (_Float16*)alloc(1024 * 512 * 2);
  _Float16* WdT1  = (_Float16*)alloc(512 * 512 * 2);
  _Float16* WdT2  = (_Float16*)alloc(128 * 512 * 2);  // 64 real rows + 64 pad rows
  _Float16* WeP1  = (_Float16*)alloc(512 * 16 * 2);
  _Float16* WeP2  = (_Float16*)alloc(512 * 16 * 2);
  _Float16* t16   = xlr16;  // decoder hidden reuses xlr buffer (dead by then)

  hipMemsetAsync(deg, 0, (size_t)N * 8, stream);

  // mega prep: x->f16 + all weight transposes in one launch
  int nx = N * 128;
  int prep_total = nx + 1024 * 128 + 1024 * 512 + 512 * 512 + 64 * 512 + 512 * 16 + 512 * 16;
  prep_kernel<<<(prep_total + 255) / 256, 256, 0, stream>>>(
      x, x16, nx, Wl1, Wr1, WlrT1, Wl2, Wr2, WlrT2,
      Wd1, WdT1, Wd2, WdT2, We1, WeP1, We2, WeP2);

  // CSR build (csr_fill also writes slot-ordered edge attrs)
  int g;
  g = (E + 255) / 256;  deg_hist_kernel<<<g, 256, 0, stream>>>(dst0, deg, E);
  scan_kernel<<<1, 1024, 0, stream>>>(deg, offs, N);
  g = (EP + 255) / 256;
  csr_fill_kernel<<<g, 256, 0, stream>>>(src0, dst0, ea, offs, deg, cnt, csr_src, eas, E, N);
  g = (N * 16 + 255) / 256;
  loop_attr_kernel<<<g, 256, 0, stream>>>(offs, deg, eas, N);

  dim3 gb(256);
  dim3 ggm((N + 127) / 128, 8);   // merged Wl|Wr: Nfull=1024
  dim3 ggd((N + 127) / 128, 4);   // decoder hidden: Nfull=512
  dim3 ggo((N + 127) / 128, 1);   // output: Nfull=64

  const int FGRID = 1024;  // 4 blocks/CU residency (VGPR 65..128 -> 4 waves/SIMD)

  // ---- GAT layer 1 ----
  gemm_f16<false, false><<<ggm, gb, 0, stream>>>(x16, WlrT1, bl1, br1, xlr16, N, 128, 1024, 1024);
  gat_fused_kernel<<<FGRID, 256, 0, stream>>>(xlr16, csr_src, offs, eas, WeP1, att1, bias1, h16, N);

  // ---- GAT layer 2 ----
  gemm_f16<false, false><<<ggm, gb, 0, stream>>>(h16, WlrT2, bl2, br2, xlr16, N, 512, 1024, 1024);
  gat_fused_kernel<<<FGRID, 256, 0, stream>>>(xlr16, csr_src, offs, eas, WeP2, att2, bias2, h16, N);

  // ---- decoder ----
  gemm_f16<true, false><<<ggd, gb, 0, stream>>>(h16, WdT1, bd1, bd1, t16, N, 512, 512, 512);
  gemm_f16<false, true><<<ggo, gb, 0, stream>>>(t16, WdT2, bd2, bd2, d_out, N, 512, 64, 64);
}

// Round 10
// 535.070 us; speedup vs baseline: 3.2095x; 1.0343x over previous
//
#include <hip/hip_runtime.h>
#include <hip/hip_fp16.h>

typedef _Float16 half8 __attribute__((ext_vector_type(8)));
typedef _Float16 half2v __attribute__((ext_vector_type(2)));
typedef float f32x4 __attribute__((ext_vector_type(4)));

#if __has_builtin(__builtin_amdgcn_fdot2)
#define FDOT2(a, b, c) __builtin_amdgcn_fdot2((a), (b), (c), false)
#else
static __device__ __forceinline__ float FDOT2(half2v a, half2v b, float c) {
  return (float)a[0] * (float)b[0] + (float)a[1] * (float)b[1] + c;
}
#endif
#define H2(v8, p) ((half2v){(v8)[2 * (p)], (v8)[2 * (p) + 1]})

// async global->LDS, 16B per lane; dest = lds base (wave-uniform) + lane*16
#define GLOAD_LDS16(gp, lp)                                                        \
  __builtin_amdgcn_global_load_lds(                                                \
      (const __attribute__((address_space(1))) void*)(gp),                         \
      (__attribute__((address_space(3))) void*)(lp), 16, 0, 0)

// 16-lane all-reduce via DPP rotate-accumulate: 4 VALU ops, no LDS pipe.
template <int CTRL>
__device__ __forceinline__ float dpp_add16(float x) {
  int y = __builtin_amdgcn_update_dpp(0, __float_as_int(x), CTRL, 0xf, 0xf, true);
  return x + __int_as_float(y);
}
__device__ __forceinline__ float rowsum16(float x) {
  x = dpp_add16<0x128>(x);  // row_ror:8
  x = dpp_add16<0x124>(x);  // row_ror:4
  x = dpp_add16<0x122>(x);  // row_ror:2
  x = dpp_add16<0x121>(x);  // row_ror:1
  return x;
}

// ---------------- mega prep kernel: x->f16 + all weight transposes ----------------
__global__ void prep_kernel(const float* __restrict__ x, _Float16* __restrict__ x16, int nx,
                            const float* __restrict__ Wl1, const float* __restrict__ Wr1,
                            _Float16* __restrict__ WlrT1,
                            const float* __restrict__ Wl2, const float* __restrict__ Wr2,
                            _Float16* __restrict__ WlrT2,
                            const float* __restrict__ Wd1, _Float16* __restrict__ WdT1,
                            const float* __restrict__ Wd2, _Float16* __restrict__ WdT2,
                            const float* __restrict__ We1, _Float16* __restrict__ WeP1,
                            const float* __restrict__ We2, _Float16* __restrict__ WeP2) {
  int i = blockIdx.x * 256 + threadIdx.x;
  if (i < nx) { x16[i] = (_Float16)x[i]; return; }
  i -= nx;
  if (i < 1024 * 128) {
    int n = i >> 7, k = i & 127;
    float v = (n < 512) ? Wl1[(size_t)k * 512 + n] : Wr1[(size_t)k * 512 + (n - 512)];
    WlrT1[i] = (_Float16)v; return;
  }
  i -= 1024 * 128;
  if (i < 1024 * 512) {
    int n = i >> 9, k = i & 511;
    float v = (n < 512) ? Wl2[(size_t)k * 512 + n] : Wr2[(size_t)k * 512 + (n - 512)];
    WlrT2[i] = (_Float16)v; return;
  }
  i -= 1024 * 512;
  if (i < 512 * 512) { int n = i >> 9, k = i & 511; WdT1[i] = (_Float16)Wd1[(size_t)k * 512 + n]; return; }
  i -= 512 * 512;
  if (i < 64 * 512)  { int n = i >> 9, k = i & 511; WdT2[i] = (_Float16)Wd2[(size_t)k * 64 + n]; return; }
  i -= 64 * 512;
  if (i < 512 * 16)  { int c = i >> 4, k = i & 15; WeP1[i] = (_Float16)We1[(size_t)k * 512 + c]; return; }
  i -= 512 * 16;
  if (i < 512 * 16)  { int c = i >> 4, k = i & 15; WeP2[i] = (_Float16)We2[(size_t)k * 512 + c]; return; }
}

// ---------------- CSR build ----------------
__global__ void deg_hist_kernel(const int* __restrict__ dst0, int* __restrict__ deg, int E) {
  int i = blockIdx.x * 256 + threadIdx.x;
  if (i < E) atomicAdd(&deg[dst0[i]], 1);
}

__global__ __launch_bounds__(1024) void scan_kernel(const int* __restrict__ deg, int* __restrict__ offs, int N) {
  __shared__ int part[1024];
  int t = threadIdx.x;
  int chunk = (N + 1023) / 1024;
  int b = t * chunk, e = min(b + chunk, N);
  int s = 0;
  for (int i = b; i < e; i++) s += deg[i] + 1;
  part[t] = s;
  __syncthreads();
  for (int off = 1; off < 1024; off <<= 1) {
    int v = (t >= off) ? part[t - off] : 0;
    __syncthreads();
    part[t] += v;
    __syncthreads();
  }
  int run = (t == 0) ? 0 : part[t - 1];
  for (int i = b; i < e; i++) { offs[i] = run; run += deg[i] + 1; }
  if (t == 1023) offs[N] = part[1023];
}

// scatter src + slot-ordered edge attr (f16) in one pass; self-loop slot marked, +12 pad
__global__ void csr_fill_kernel(const int* __restrict__ src0, const int* __restrict__ dst0,
                                const float* __restrict__ ea,
                                const int* __restrict__ offs, const int* __restrict__ deg,
                                int* __restrict__ cnt, int* __restrict__ csr_src,
                                _Float16* __restrict__ eas, int E, int N) {
  int i = blockIdx.x * 256 + threadIdx.x;
  if (i < 12) {
    csr_src[E + N + i] = 0;
#pragma unroll
    for (int k = 0; k < 16; k++) eas[(size_t)(E + N + i) * 16 + k] = (_Float16)0.f;
  }
  if (i < E) {
    int d = dst0[i];
    int p = offs[d] + atomicAdd(&cnt[d], 1);
    csr_src[p] = src0[i];
    const float* s = ea + (size_t)i * 16;
    half8 h0, h1;
#pragma unroll
    for (int k = 0; k < 8; k++) { h0[k] = (_Float16)s[k]; h1[k] = (_Float16)s[k + 8]; }
    *(half8*)(eas + (size_t)p * 16) = h0;
    *(half8*)(eas + (size_t)p * 16 + 8) = h1;
  } else if (i < E + N) {
    int v = i - E;
    csr_src[offs[v] + deg[v]] = v;  // self-loop; attrs filled by loop_attr_kernel
  }
}

// self-loop attr = mean of real incoming slots (sequential f16 reads), written into its slot
__global__ void loop_attr_kernel(const int* __restrict__ offs, const int* __restrict__ deg,
                                 _Float16* __restrict__ eas, int N) {
  int i = blockIdx.x * 256 + threadIdx.x;
  if (i >= N * 16) return;
  int v = i >> 4, k = i & 15;
  int b = offs[v], dg = deg[v];
  float s = 0.f;
  for (int j = 0; j < dg; j++) s += (float)eas[((size_t)(b + j)) * 16 + k];
  eas[((size_t)(b + dg)) * 16 + k] = (_Float16)(s / fmaxf((float)dg, 1.0f));
}

// ---------------- GEMM: C[M,Nfull] = A[M,K](f16) * BT[Nfull,K](f16) + bias ----------------
// m97-style staging: global_load_lds dwordx4, contiguous [128][32]-half LDS tiles (no pad —
// DMA dest is wave-uniform base + lane*16). A/BT buffers MUST be padded to 128-row multiples.
template <bool RELU, bool OUT_F32>
__global__ __launch_bounds__(256) void gemm_f16(const _Float16* __restrict__ A,
                                                const _Float16* __restrict__ BT,
                                                const float* __restrict__ biasA,
                                                const float* __restrict__ biasB,
                                                void* __restrict__ C,
                                                int M, int K, int Nfull, int ldc) {
  __shared__ _Float16 As[128 * 32];
  __shared__ _Float16 Bs[128 * 32];
  int t = threadIdx.x;
  int m0 = blockIdx.x * 128;
  int n0 = blockIdx.y * 128;
  int l = t & 63, w = t >> 6;
  int wm = w & 1, wn = w >> 1;
  int lr = l & 15, lq = l >> 4;

  f32x4 acc[4][4];
#pragma unroll
  for (int i = 0; i < 4; i++)
#pragma unroll
    for (int j = 0; j < 4; j++) acc[i][j] = (f32x4){0.f, 0.f, 0.f, 0.f};

  // staging: wave w covers rows [w*32, w*32+32); lane i -> row w*32+i/4, halves (i%4)*8
  int r0 = w * 32 + (l >> 2);
  int cb = (l & 3) * 8;
  const _Float16* Ap = A + (size_t)(m0 + r0) * K + cb;
  const _Float16* Bp = BT + (size_t)(n0 + r0) * K + cb;
  _Float16* AsW = As + w * 32 * 32;   // wave-uniform LDS bases
  _Float16* BsW = Bs + w * 32 * 32;

  for (int kk = 0; kk < K; kk += 32) {
    GLOAD_LDS16(Ap, AsW);
    GLOAD_LDS16(Ap + (size_t)16 * K, AsW + 16 * 32);
    GLOAD_LDS16(Bp, BsW);
    GLOAD_LDS16(Bp + (size_t)16 * K, BsW + 16 * 32);
    Ap += 32; Bp += 32;
    __syncthreads();
    half8 af[4], bf[4];
#pragma unroll
    for (int mi = 0; mi < 4; mi++) af[mi] = *(const half8*)&As[(wm * 64 + mi * 16 + lr) * 32 + lq * 8];
#pragma unroll
    for (int ni = 0; ni < 4; ni++) bf[ni] = *(const half8*)&Bs[(wn * 64 + ni * 16 + lr) * 32 + lq * 8];
#pragma unroll
    for (int mi = 0; mi < 4; mi++)
#pragma unroll
      for (int ni = 0; ni < 4; ni++)
        acc[mi][ni] = __builtin_amdgcn_mfma_f32_16x16x32_f16(af[mi], bf[ni], acc[mi][ni], 0, 0, 0);
    __syncthreads();
  }

#pragma unroll
  for (int ni = 0; ni < 4; ni++) {
    int col = n0 + wn * 64 + ni * 16 + lr;
    if (col >= Nfull) continue;
    float bv = (col < 512) ? biasA[col] : biasB[col - 512];
#pragma unroll
    for (int mi = 0; mi < 4; mi++) {
#pragma unroll
      for (int r = 0; r < 4; r++) {
        int row = m0 + wm * 64 + mi * 16 + lq * 4 + r;
        if (row >= M) continue;
        float v = acc[mi][ni][r] + bv;
        if (RELU) v = fmaxf(v, 0.f);
        if (OUT_F32) ((float*)C)[(size_t)row * ldc + col] = v;
        else ((_Float16*)C)[(size_t)row * ldc + col] = (_Float16)v;
      }
    }
  }
}

// ---------------- fused GATv2 edge pass ----------------

__device__ __forceinline__ void edge_compute(
    half8 xs, half8 e0, half8 e1,
    const half8 Wf0[8], const half8 Wf1[8],
    const float attf[8], const float xrf[8],
    float& m, float& den, float acc[8]) {
  float xsf[8];
#pragma unroll
  for (int jj = 0; jj < 8; jj++) xsf[jj] = (float)xs[jj];
  float partial = 0.f;
#pragma unroll
  for (int jj = 0; jj < 8; jj++) {
    float ef = xsf[jj] + xrf[jj];
#pragma unroll
    for (int p = 0; p < 4; p++) ef = FDOT2(H2(e0, p), H2(Wf0[jj], p), ef);
#pragma unroll
    for (int p = 0; p < 4; p++) ef = FDOT2(H2(e1, p), H2(Wf1[jj], p), ef);
    float val = fmaxf(ef, 0.2f * ef);
    partial = fmaf(val, attf[jj], partial);
  }
  partial = rowsum16(partial);
  float mn = fmaxf(m, partial);
  float sc = __expf(m - mn);
  float al = __expf(partial - mn);
  den = den * sc + al;
#pragma unroll
  for (int jj = 0; jj < 8; jj++) acc[jj] = fmaf(acc[jj], sc, al * xsf[jj]);
  m = mn;
}

// wave per node, online softmax, 3-slot rotating pipeline. Node index forced
// uniform via readfirstlane so offs/csr_src/eas loads go to the scalar pipe
// (round 9: VGPR 84->64, SGPR 32->64). KERNEL BODY MUST STAY AT VGPR<=64 —
// that's the 8-waves/SIMD boundary (m69); any extra slot/unroll halves occupancy.
__global__ __launch_bounds__(256) void gat_fused_kernel(
    const _Float16* __restrict__ xlr,     // [Npad][1024]: 0..511 xl, 512..1023 xr
    const int* __restrict__ csr_src, const int* __restrict__ offs,
    const _Float16* __restrict__ eas,     // [EP+12][16] slot-ordered
    const _Float16* __restrict__ WeP,     // [512][16]
    const float* __restrict__ att, const float* __restrict__ bias,
    _Float16* __restrict__ hout, int N) {
  int l = threadIdx.x & 63;
  int h = l >> 4;
  int c0 = l * 8;

  half8 Wf0[8], Wf1[8];
#pragma unroll
  for (int j = 0; j < 8; j++) {
    Wf0[j] = *(const half8*)(WeP + (size_t)(c0 + j) * 16);
    Wf1[j] = *(const half8*)(WeP + (size_t)(c0 + j) * 16 + 8);
  }
  float attf[8];
  const float* attp = att + h * 128 + (l & 15) * 8;
#pragma unroll
  for (int j = 0; j < 8; j++) attf[j] = attp[j];

  int wid = blockIdx.x * 4 + (threadIdx.x >> 6);
  int nw = gridDim.x * 4;

  for (int v0 = wid; v0 < N; v0 += nw) {
    int v = __builtin_amdgcn_readfirstlane(v0);   // wave-uniform in SGPR
    int b = offs[v], e2 = offs[v + 1];
    half8 xrv = *(const half8*)(xlr + (size_t)v * 1024 + 512 + c0);
    float xrf[8];
#pragma unroll
    for (int jj = 0; jj < 8; jj++) xrf[jj] = (float)xrv[jj];

    int s0 = csr_src[b], s1 = csr_src[b + 1], s2 = csr_src[b + 2];
    half8 xs0 = *(const half8*)(xlr + (size_t)s0 * 1024 + c0);
    half8 a00 = *(const half8*)(eas + (size_t)b * 16);
    half8 a01 = *(const half8*)(eas + (size_t)b * 16 + 8);
    half8 xs1 = *(const half8*)(xlr + (size_t)s1 * 1024 + c0);
    half8 a10 = *(const half8*)(eas + (size_t)(b + 1) * 16);
    half8 a11 = *(const half8*)(eas + (size_t)(b + 1) * 16 + 8);
    half8 xs2 = *(const half8*)(xlr + (size_t)s2 * 1024 + c0);
    half8 a20 = *(const half8*)(eas + (size_t)(b + 2) * 16);
    half8 a21 = *(const half8*)(eas + (size_t)(b + 2) * 16 + 8);
    int s3 = csr_src[b + 3], s4 = csr_src[b + 4], s5 = csr_src[b + 5];

    float m = -1e30f, den = 0.f;
    float acc[8];
#pragma unroll
    for (int j = 0; j < 8; j++) acc[j] = 0.f;

    for (int j = b; j < e2; j += 3) {
      edge_compute(xs0, a00, a01, Wf0, Wf1, attf, xrf, m, den, acc);
      xs0 = *(const half8*)(xlr + (size_t)s3 * 1024 + c0);
      a00 = *(const half8*)(eas + (size_t)(j + 3) * 16);
      a01 = *(const half8*)(eas + (size_t)(j + 3) * 16 + 8);
      s3 = csr_src[j + 6];
      if (j + 1 < e2)
        edge_compute(xs1, a10, a11, Wf0, Wf1, attf, xrf, m, den, acc);
      xs1 = *(const half8*)(xlr + (size_t)s4 * 1024 + c0);
      a10 = *(const half8*)(eas + (size_t)(j + 4) * 16);
      a11 = *(const half8*)(eas + (size_t)(j + 4) * 16 + 8);
      s4 = csr_src[j + 7];
      if (j + 2 < e2)
        edge_compute(xs2, a20, a21, Wf0, Wf1, attf, xrf, m, den, acc);
      xs2 = *(const half8*)(xlr + (size_t)s5 * 1024 + c0);
      a20 = *(const half8*)(eas + (size_t)(j + 5) * 16);
      a21 = *(const half8*)(eas + (size_t)(j + 5) * 16 + 8);
      s5 = csr_src[j + 8];
    }
    float rd = 1.f / (den + 1e-16f);
    half8 o;
#pragma unroll
    for (int jj = 0; jj < 8; jj++) o[jj] = (_Float16)(fmaf(acc[jj], rd, bias[c0 + jj]));
    *(half8*)(hout + (size_t)v * 512 + c0) = o;
  }
}

// ---------------- launcher ----------------

extern "C" void kernel_launch(void* const* d_in, const int* in_sizes, int n_in,
                              void* d_out, int out_size, void* d_ws, size_t ws_size,
                              hipStream_t stream) {
  (void)n_in; (void)out_size; (void)ws_size;
  const float* x    = (const float*)d_in[0];
  const int*   ei   = (const int*)d_in[1];
  const float* ea   = (const float*)d_in[2];
  const float* Wl1  = (const float*)d_in[3];
  const float* bl1  = (const float*)d_in[4];
  const float* Wr1  = (const float*)d_in[5];
  const float* br1  = (const float*)d_in[6];
  const float* We1  = (const float*)d_in[7];
  const float* att1 = (const float*)d_in[8];
  const float* bias1= (const float*)d_in[9];
  const float* Wl2  = (const float*)d_in[10];
  const float* bl2  = (const float*)d_in[11];
  const float* Wr2  = (const float*)d_in[12];
  const float* br2  = (const float*)d_in[13];
  const float* We2  = (const float*)d_in[14];
  const float* att2 = (const float*)d_in[15];
  const float* bias2= (const float*)d_in[16];
  const float* Wd1  = (const float*)d_in[17];
  const float* bd1  = (const float*)d_in[18];
  const float* Wd2  = (const float*)d_in[19];
  const float* bd2  = (const float*)d_in[20];

  const int N = in_sizes[0] / 128;
  const int E = in_sizes[1] / 2;
  const int EP = E + N;
  const int Npad = (N + 127) & ~127;   // staging reads are unguarded -> pad row buffers
  const int* src0 = ei;
  const int* dst0 = ei + E;

  char* ws = (char*)d_ws;
  size_t off = 0;
  auto alloc = [&](size_t bytes) -> void* {
    void* p = ws + off;
    off += (bytes + 255) & ~(size_t)255;
    return p;
  };

  int*   deg    = (int*)alloc((size_t)N * 8);
  int*   cnt    = deg + N;
  int*   offs   = (int*)alloc(((size_t)N + 1) * 4);
  int*   csr_src= (int*)alloc(((size_t)EP + 12) * 4);
  _Float16* eas = (_Float16*)alloc(((size_t)EP + 12) * 16 * 2);
  _Float16* x16   = (_Float16*)alloc((size_t)Npad * 128 * 2);
  _Float16* xlr16 = (_Float16*)alloc((size_t)Npad * 1024 * 2);
  _Float16* h16   = (_Float16*)alloc((size_t)Npad * 512 * 2);
  _Float16* WlrT1 = (_Float16*)alloc(1024 * 128 * 2);
  _Float16* WlrT2 = (_Float16*)alloc(1024 * 512 * 2);
  _Float16* WdT1  = (_Float16*)alloc(512 * 512 * 2);
  _Float16* WdT2  = (_Float16*)alloc(128 * 512 * 2);  // 64 real rows + 64 pad rows
  _Float16* WeP1  = (_Float16*)alloc(512 * 16 * 2);
  _Float16* WeP2  = (_Float16*)alloc(512 * 16 * 2);
  _Float16* t16   = xlr16;  // decoder hidden reuses xlr buffer (dead by then)

  hipMemsetAsync(deg, 0, (size_t)N * 8, stream);

  // mega prep: x->f16 + all weight transposes in one launch
  int nx = N * 128;
  int prep_total = nx + 1024 * 128 + 1024 * 512 + 512 * 512 + 64 * 512 + 512 * 16 + 512 * 16;
  prep_kernel<<<(prep_total + 255) / 256, 256, 0, stream>>>(
      x, x16, nx, Wl1, Wr1, WlrT1, Wl2, Wr2, WlrT2,
      Wd1, WdT1, Wd2, WdT2, We1, WeP1, We2, WeP2);

  // CSR build (csr_fill also writes slot-ordered edge attrs)
  int g;
  g = (E + 255) / 256;  deg_hist_kernel<<<g, 256, 0, stream>>>(dst0, deg, E);
  scan_kernel<<<1, 1024, 0, stream>>>(deg, offs, N);
  g = (EP + 255) / 256;
  csr_fill_kernel<<<g, 256, 0, stream>>>(src0, dst0, ea, offs, deg, cnt, csr_src, eas, E, N);
  g = (N * 16 + 255) / 256;
  loop_attr_kernel<<<g, 256, 0, stream>>>(offs, deg, eas, N);

  dim3 gb(256);
  dim3 ggm((N + 127) / 128, 8);   // merged Wl|Wr: Nfull=1024
  dim3 ggd((N + 127) / 128, 4);   // decoder hidden: Nfull=512
  dim3 ggo((N + 127) / 128, 1);   // output: Nfull=64

  const int FGRID = 2048;  // 8 blocks/CU co-resident (VGPR=64 -> 8 waves/SIMD; round-9 fact)

  // ---- GAT layer 1 ----
  gemm_f16<false, false><<<ggm, gb, 0, stream>>>(x16, WlrT1, bl1, br1, xlr16, N, 128, 1024, 1024);
  gat_fused_kernel<<<FGRID, 256, 0, stream>>>(xlr16, csr_src, offs, eas, WeP1, att1, bias1, h16, N);

  // ---- GAT layer 2 ----
  gemm_f16<false, false><<<ggm, gb, 0, stream>>>(h16, WlrT2, bl2, br2, xlr16, N, 512, 1024, 1024);
  gat_fused_kernel<<<FGRID, 256, 0, stream>>>(xlr16, csr_src, offs, eas, WeP2, att2, bias2, h16, N);

  // ---- decoder ----
  gemm_f16<true, false><<<ggd, gb, 0, stream>>>(h16, WdT1, bd1, bd1, t16, N, 512, 512, 512);
  gemm_f16<false, true><<<ggo, gb, 0, stream>>>(t16, WdT2, bd2, bd2, d_out, N, 512, 64, 64);
}